// Round 10
// baseline (1646.281 us; speedup 1.0000x reference)
//
#include <hip/hip_runtime.h>
#include <math.h>

typedef _Float16 half_t;
typedef __attribute__((ext_vector_type(8))) _Float16 f16x8;
typedef __attribute__((ext_vector_type(4))) _Float16 f16x4;
typedef __attribute__((ext_vector_type(4))) float f32x4;
typedef __attribute__((ext_vector_type(16))) float f32x16;

#define MFMA __builtin_amdgcn_mfma_f32_16x16x32_f16
#define MFMA32 __builtin_amdgcn_mfma_f32_32x32x16_f16
#define K1C (0.08838834764831845f * 1.4426950408889634f)  // SCALE * log2(e)
#define RLO (1.0f / 2048.0f)

// async global->LDS, 16B per lane (linear dest = base + lane*16)
__device__ inline void gld16(const void* g, void* l) {
  __builtin_amdgcn_global_load_lds(
      (const __attribute__((address_space(1))) uint32_t*)g,
      (__attribute__((address_space(3))) uint32_t*)l, 16, 0, 0);
}

// ---------- split fp32 -> fp16 hi + fp16 lo*2^11 ----------
__global__ __launch_bounds__(256) void split_x(const float* __restrict__ X,
                                               half_t* __restrict__ Xh,
                                               half_t* __restrict__ Xl) {
  size_t i = (size_t)blockIdx.x * 256 + threadIdx.x;
  const size_t stride = (size_t)gridDim.x * 256;
  for (size_t p = i; p < 4194304; p += stride) {
    f32x4 v = ((const f32x4*)X)[p];
    f16x4 h, l;
#pragma unroll
    for (int j = 0; j < 4; ++j) {
      half_t hh = (half_t)v[j];
      h[j] = hh;
      l[j] = (half_t)((v[j] - (float)hh) * 2048.0f);
    }
    ((f16x4*)Xh)[p] = h;
    ((f16x4*)Xl)[p] = l;
  }
}

// ---------- W[2048][2048] -> Wt[n][k] split halves ----------
__global__ __launch_bounds__(256) void wtrans_split(const float* __restrict__ W,
                                                    half_t* __restrict__ Wh,
                                                    half_t* __restrict__ Wl) {
  __shared__ float T[64][68];
  const int tid = threadIdx.x;
  const int k0 = blockIdx.x * 64, n0 = blockIdx.y * 64;
#pragma unroll
  for (int t = 0; t < 4; ++t) {
    int s = t * 256 + tid;
    int kr = s >> 4, nc = (s & 15) * 4;
    f32x4 v = *(const f32x4*)&W[(size_t)(k0 + kr) * 2048 + n0 + nc];
#pragma unroll
    for (int j = 0; j < 4; ++j) T[nc + j][kr] = v[j];
  }
  __syncthreads();
#pragma unroll
  for (int t = 0; t < 4; ++t) {
    int s = t * 256 + tid;
    int nr = s >> 4, kc = (s & 15) * 4;
    f16x4 h, l;
#pragma unroll
    for (int j = 0; j < 4; ++j) {
      float q = T[nr][kc + j];
      half_t hh = (half_t)q;
      h[j] = hh;
      l[j] = (half_t)((q - (float)hh) * 2048.0f);
    }
    *(f16x4*)&Wh[(size_t)(n0 + nr) * 2048 + k0 + kc] = h;
    *(f16x4*)&Wl[(size_t)(n0 + nr) * 2048 + k0 + kc] = l;
  }
}

// ---------- projection GEMM (32x32x16 MFMA): C = X @ Wt^T, split-fp16 ----------
#define STAGE_P(nb, kn) do {                                                  \
    _Pragma("unroll")                                                         \
    for (int t_ = 0; t_ < 2; ++t_) {                                          \
      int s_ = t_ * 256 + tid;                                                \
      int row_ = s_ >> 2;                                                     \
      int lch_ = (s_ & 3) ^ ((row_ >> 1) & 3);  /* pre-swizzled source */     \
      size_t ga_ = (size_t)(m0 + row_) * 2048 + (kn) + lch_ * 8;              \
      size_t gb_ = (size_t)(n0 + row_) * 2048 + (kn) + lch_ * 8;              \
      gld16(&Xh[ga_], &sm[nb][s_ * 8]);                                       \
      gld16(&Wh[gb_], &sm[nb][4096 + s_ * 8]);                                \
      if constexpr (MODE == 0) {                                              \
        gld16(&Xl[ga_], &sm[nb][8192 + s_ * 8]);                              \
        gld16(&Wl[gb_], &sm[nb][12288 + s_ * 8]);                             \
      }                                                                       \
    }                                                                         \
  } while (0)

template <int MODE>
__global__ __launch_bounds__(256, MODE == 0 ? 2 : 4) void proj_mfma(
    const half_t* __restrict__ Xh, const half_t* __restrict__ Xl,
    const half_t* __restrict__ Wh, const half_t* __restrict__ Wl,
    half_t* __restrict__ Ch, half_t* __restrict__ Cl) {
  __shared__ half_t sm[2][MODE == 0 ? 16384 : 8192];
  const int tid = threadIdx.x;
  const int lid = blockIdx.x;
  const int swz = (lid & 7) * 128 + (lid >> 3);  // bijective XCD swizzle (1024%8==0)
  const int m0 = (swz >> 4) << 7, n0 = (swz & 15) << 7;
  const int w = tid >> 6, lane = tid & 63, r5 = lane & 31, hi = lane >> 5;
  const int wr = w >> 1, wc = w & 1;
  const int rsw = (r5 >> 1) & 3;
  f32x16 acc0[2][2], accX[2][2];
#pragma unroll
  for (int i = 0; i < 2; ++i)
#pragma unroll
    for (int j = 0; j < 2; ++j) {
#pragma unroll
      for (int r = 0; r < 16; ++r) { acc0[i][j][r] = 0.f; accX[i][j][r] = 0.f; }
    }
  STAGE_P(0, 0);
  __syncthreads();
  for (int k0 = 0; k0 < 2048; k0 += 32) {
    const int buf = (k0 >> 5) & 1;
    if (k0 < 2016) STAGE_P(buf ^ 1, k0 + 32);
#pragma unroll
    for (int ks = 0; ks < 2; ++ks) {
      const int ch = ((ks << 1) | hi) ^ rsw;
      f16x8 a0[2], a1[2], b0[2], b1[2];
#pragma unroll
      for (int i = 0; i < 2; ++i) {
        int ar = wr * 64 + i * 32 + r5;
        int br = wc * 64 + i * 32 + r5;
        a0[i] = *(const f16x8*)&sm[buf][ar * 32 + ch * 8];
        b0[i] = *(const f16x8*)&sm[buf][4096 + br * 32 + ch * 8];
        if constexpr (MODE == 0) {
          a1[i] = *(const f16x8*)&sm[buf][8192 + ar * 32 + ch * 8];
          b1[i] = *(const f16x8*)&sm[buf][12288 + br * 32 + ch * 8];
        }
      }
#pragma unroll
      for (int i = 0; i < 2; ++i)
#pragma unroll
        for (int j = 0; j < 2; ++j) {
          acc0[i][j] = MFMA32(a0[i], b0[j], acc0[i][j], 0, 0, 0);
          if constexpr (MODE == 0) {
            accX[i][j] = MFMA32(a0[i], b1[j], accX[i][j], 0, 0, 0);
            accX[i][j] = MFMA32(a1[i], b0[j], accX[i][j], 0, 0, 0);
          }
        }
    }
    __syncthreads();
  }
#pragma unroll
  for (int i = 0; i < 2; ++i)
#pragma unroll
    for (int j = 0; j < 2; ++j) {
      int mb = m0 + wr * 64 + i * 32 + 4 * hi;
      int n = n0 + wc * 64 + j * 32 + r5;
#pragma unroll
      for (int r = 0; r < 16; ++r) {
        int mrow = mb + (r & 3) + 8 * (r >> 2);
        float q;
        if constexpr (MODE == 0) q = acc0[i][j][r] + accX[i][j][r] * RLO;
        else q = acc0[i][j][r];
        half_t hh = (half_t)q;
        size_t o = (size_t)mrow * 2048 + n;
        Ch[o] = hh;
        if constexpr (MODE == 0) Cl[o] = (half_t)((q - (float)hh) * 2048.0f);
      }
    }
}

// ---------- V[bh][k][d] -> Vt[bh][d][k] ----------
__global__ __launch_bounds__(256) void transpose_v(const half_t* __restrict__ V,
                                                   half_t* __restrict__ Vt) {
  __shared__ half_t T[128 * 128];
  const int tid = threadIdx.x;
  const int bh = blockIdx.y, k0 = blockIdx.x * 128;
  const size_t base = (size_t)bh << 18;
#pragma unroll
  for (int t = 0; t < 8; ++t) {
    int s = t * 256 + tid;
    int kr = s >> 4, ch = s & 15;
    int pc = ch ^ ((kr >> 3) & 15);
    *(f16x8*)&T[kr * 128 + pc * 8] =
        *(const f16x8*)&V[base + (size_t)(k0 + kr) * 128 + ch * 8];
  }
  __syncthreads();
#pragma unroll
  for (int t = 0; t < 8; ++t) {
    int s = t * 256 + tid;
    int d = s >> 4, kc = s & 15;
    f16x8 o;
#pragma unroll
    for (int j = 0; j < 8; ++j) {
      int kr = kc * 8 + j;
      int pc = (d >> 3) ^ (kc & 15);
      o[j] = T[kr * 128 + pc * 8 + (d & 7)];
    }
    *(f16x8*)&Vt[base + (size_t)d * 2048 + k0 + kc * 8] = o;
  }
}

// ---------- column-softmax stats, q-split x4: partial (m,z) per split ----------
#define STAGE_Q(nb, qn) do {                                                  \
    int r0_ = tid >> 4, cl0_ = tid & 15;                                      \
    size_t o0_ = base + (size_t)((qn) + r0_) * 128 + ((cl0_ ^ r0_) << 3);     \
    gld16(&Qh[o0_], &sQ0[nb][tid << 3]);                                      \
    gld16(&Ql[o0_], &sQ1[nb][tid << 3]);                                      \
    int r1_ = 16 + r0_;                                                       \
    size_t o1_ = base + (size_t)((qn) + r1_) * 128 + ((cl0_ ^ (r1_ & 15)) << 3); \
    gld16(&Qh[o1_], &sQ0[nb][(256 + tid) << 3]);                              \
    gld16(&Ql[o1_], &sQ1[nb][(256 + tid) << 3]);                              \
  } while (0)

__global__ __launch_bounds__(256, 2) void stats_mfma(
    const half_t* __restrict__ Qh, const half_t* __restrict__ Ql,
    const half_t* __restrict__ Kh, const half_t* __restrict__ Kl,
    float* __restrict__ Mp, float* __restrict__ Zp) {
  __shared__ half_t sQ0[2][4096], sQ1[2][4096];
  const int tid = threadIdx.x;
  const int w = tid >> 6, lane = tid & 63, c = lane & 15, g = lane >> 4;
  const int lid = blockIdx.y * 8 + blockIdx.x;
  const int bh = (lid & 7) * 8 + ((lid >> 3) & 7);   // XCD-swizzled
  const int xb = lid >> 6;
  const int qstart = blockIdx.z << 9;                 // 512 q per split
  const size_t base = (size_t)bh << 18;
  const int kb = xb * 256 + w * 64;
  f32x4 z4 = {0.f, 0.f, 0.f, 0.f};
  f16x8 ka0[4][4], ka1[4][4];
#pragma unroll
  for (int kt = 0; kt < 4; ++kt)
#pragma unroll
    for (int ds = 0; ds < 4; ++ds) {
      size_t a = base + (size_t)(kb + kt * 16 + c) * 128 + ds * 32 + g * 8;
      ka0[kt][ds] = *(const f16x8*)&Kh[a];
      ka1[kt][ds] = *(const f16x8*)&Kl[a];
    }
  float m[4][4], z[4][4];
#pragma unroll
  for (int kt = 0; kt < 4; ++kt)
#pragma unroll
    for (int r = 0; r < 4; ++r) { m[kt][r] = -INFINITY; z[kt][r] = 0.f; }
  STAGE_Q(0, qstart);
  __syncthreads();
  for (int t = 0; t < 16; ++t) {
    const int buf = t & 1;
    if (t < 15) STAGE_Q(buf ^ 1, qstart + ((t + 1) << 5));
#pragma unroll
    for (int qh = 0; qh < 2; ++qh) {
      f16x8 q0v[4], q1v[4];
#pragma unroll
      for (int ds = 0; ds < 4; ++ds) {
        int off = ((qh << 4) | c) * 128 + ((((ds << 2) | g) ^ c) << 3);
        q0v[ds] = *(const f16x8*)&sQ0[buf][off];
        q1v[ds] = *(const f16x8*)&sQ1[buf][off];
      }
#pragma unroll
      for (int kt = 0; kt < 4; ++kt) {
        f32x4 A0 = z4, AX = z4;
#pragma unroll
        for (int ds = 0; ds < 4; ++ds) {
          A0 = MFMA(ka0[kt][ds], q0v[ds], A0, 0, 0, 0);
          AX = MFMA(ka0[kt][ds], q1v[ds], AX, 0, 0, 0);
          AX = MFMA(ka1[kt][ds], q0v[ds], AX, 0, 0, 0);
        }
#pragma unroll
        for (int r = 0; r < 4; ++r) {
          float tt = (A0[r] + AX[r] * RLO) * K1C;
          float mo = m[kt][r];
          float mn = fmaxf(mo, tt);
          float e = __builtin_amdgcn_exp2f(fminf(mo, tt) - mn);
          z[kt][r] = (tt <= mo) ? (z[kt][r] + e) : (z[kt][r] * e + 1.0f);
          m[kt][r] = mn;
        }
      }
    }
    __syncthreads();
  }
#pragma unroll
  for (int mask = 1; mask < 16; mask <<= 1)
#pragma unroll
    for (int kt = 0; kt < 4; ++kt)
#pragma unroll
      for (int r = 0; r < 4; ++r) {
        float mo = __shfl_xor(m[kt][r], mask, 64);
        float zo = __shfl_xor(z[kt][r], mask, 64);
        float mn = fmaxf(m[kt][r], mo);
        z[kt][r] = z[kt][r] * __builtin_amdgcn_exp2f(m[kt][r] - mn) +
                   zo * __builtin_amdgcn_exp2f(mo - mn);
        m[kt][r] = mn;
      }
  if (c == 0) {
    const int pb = (blockIdx.z << 17) + (bh << 11);
#pragma unroll
    for (int kt = 0; kt < 4; ++kt)
#pragma unroll
      for (int r = 0; r < 4; ++r) {
        int idx = pb + kb + kt * 16 + (g << 2) + r;
        Mp[idx] = m[kt][r];
        Zp[idx] = z[kt][r];
      }
  }
}

// ---------- merge 4 q-split partials -> C2 = m* + log2(sum z) ----------
__global__ __launch_bounds__(256) void stats_finalize(const float* __restrict__ Mp,
                                                      const float* __restrict__ Zp,
                                                      float* __restrict__ C2) {
  int i = blockIdx.x * 256 + threadIdx.x;  // 0..131071
  float m = Mp[i], z = Zp[i];
#pragma unroll
  for (int s = 1; s < 4; ++s) {
    float ms = Mp[(s << 17) + i], zs = Zp[(s << 17) + i];
    float mn = fmaxf(m, ms);
    z = z * __builtin_amdgcn_exp2f(m - mn) + zs * __builtin_amdgcn_exp2f(ms - mn);
    m = mn;
  }
  C2[i] = m + __builtin_amdgcn_logf(z);
}

// ---------- attention: 2 q-tiles (32 q) per wave, K reads amortized over both;
// LDS kept under the ~70KB 2-block/CU residency threshold by dropping the sC2
// stage (C2 f32x4 loads come straight from global/L2, hoisted to iter start).
#define STAGE_ATTN(nb, ktn) do {                                              \
    int r_ = tid >> 4, chl_ = tid & 15;                                       \
    size_t ro_ = base + (size_t)((ktn) + r_) * 128 + ((chl_ ^ (r_ & 15)) << 3); \
    gld16(&Kh[ro_], &sKh[nb][tid << 3]);                                      \
    gld16(&Kl[ro_], &sKl[nb][tid << 3]);                                      \
    int d_ = tid >> 2, cvl_ = tid & 3;                                        \
    gld16(&Vt[base + (size_t)d_ * 2048 + (ktn) + ((cvl_ ^ ((d_ >> 1) & 3)) << 3)], \
          &sVs[nb][tid << 3]);                                                \
  } while (0)

__global__ __launch_bounds__(512, 4) void attn_mfma(
    const half_t* __restrict__ Qh, const half_t* __restrict__ Ql,
    const half_t* __restrict__ Kh, const half_t* __restrict__ Kl,
    const half_t* __restrict__ Vt, const float* __restrict__ C2,
    float* __restrict__ O) {
  __shared__ half_t sKh[2][4096], sKl[2][4096], sVs[2][4096];
  __shared__ half_t sP[8][2][16][40];
  const int tid = threadIdx.x;
  const int w = tid >> 6, lane = tid & 63, c = lane & 15, g = lane >> 4;
  const int lid = blockIdx.y * 8 + blockIdx.x;
  const int bh = (lid & 7) * 8 + ((lid >> 3) & 7);   // XCD-swizzled
  const int qx = lid >> 6;
  const size_t base = (size_t)bh << 18;
  const int qb = qx * 256 + w * 32;                   // 32 q per wave
  const float* c2base = C2 + ((size_t)bh << 11) + (g << 2);
  f32x4 z4 = {0.f, 0.f, 0.f, 0.f};
  f16x8 qf0[2][4], qf1[2][4];
#pragma unroll
  for (int qq = 0; qq < 2; ++qq)
#pragma unroll
    for (int ds = 0; ds < 4; ++ds) {
      size_t a = base + (size_t)(qb + qq * 16 + c) * 128 + ds * 32 + g * 8;
      qf0[qq][ds] = *(const f16x8*)&Qh[a];
      qf1[qq][ds] = *(const f16x8*)&Ql[a];
    }
  f32x4 Oacc[2][8];
#pragma unroll
  for (int qq = 0; qq < 2; ++qq)
#pragma unroll
    for (int dt = 0; dt < 8; ++dt) Oacc[qq][dt] = z4;
  STAGE_ATTN(0, 0);
  __syncthreads();
  for (int t = 0; t < 64; ++t) {
    const int buf = t & 1;
    const int kt = t << 5;
    if (t < 63) STAGE_ATTN(buf ^ 1, kt + 32);
    // hoisted C2 loads (L2-hot, independent of scores)
    f32x4 c2a = *(const f32x4*)&c2base[kt];
    f32x4 c2b = *(const f32x4*)&c2base[kt + 16];
#pragma unroll
    for (int h = 0; h < 2; ++h) {
      f32x4 A0[2] = {z4, z4}, AX[2] = {z4, z4};
#pragma unroll
      for (int ds = 0; ds < 4; ++ds) {
        int off = ((h << 4) | c) * 128 + ((((ds << 2) | g) ^ c) << 3);
        f16x8 k0v = *(const f16x8*)&sKh[buf][off];
        f16x8 k1v = *(const f16x8*)&sKl[buf][off];
#pragma unroll
        for (int qq = 0; qq < 2; ++qq) {
          A0[qq] = MFMA(k0v, qf0[qq][ds], A0[qq], 0, 0, 0);
          AX[qq] = MFMA(k0v, qf1[qq][ds], AX[qq], 0, 0, 0);
          AX[qq] = MFMA(k1v, qf0[qq][ds], AX[qq], 0, 0, 0);
        }
      }
      f32x4 c2v = h ? c2b : c2a;
#pragma unroll
      for (int qq = 0; qq < 2; ++qq) {
        f16x4 pv;
#pragma unroll
        for (int r = 0; r < 4; ++r)
          pv[r] = (half_t)__builtin_amdgcn_exp2f(
              (A0[qq][r] + AX[qq][r] * RLO) * K1C - c2v[r]);
        *(f16x4*)&sP[w][qq][c][(h << 4) + (g << 2)] = pv;
      }
    }
    f16x8 pa0 = *(const f16x8*)&sP[w][0][c][g << 3];
    f16x8 pa1 = *(const f16x8*)&sP[w][1][c][g << 3];
#pragma unroll
    for (int dt = 0; dt < 8; ++dt) {
      int dd = (dt << 4) + c;
      f16x8 vb = *(const f16x8*)&sVs[buf][dd * 32 + ((g ^ ((dd >> 1) & 3)) << 3)];
      Oacc[0][dt] = MFMA(pa0, vb, Oacc[0][dt], 0, 0, 0);
      Oacc[1][dt] = MFMA(pa1, vb, Oacc[1][dt], 0, 0, 0);
    }
    __syncthreads();
  }
#pragma unroll
  for (int qq = 0; qq < 2; ++qq)
#pragma unroll
    for (int dt = 0; dt < 8; ++dt)
#pragma unroll
      for (int r = 0; r < 4; ++r)
        O[base + (size_t)(qb + qq * 16 + (g << 2) + r) * 128 + (dt << 4) + c] =
            Oacc[qq][dt][r];
}

extern "C" void kernel_launch(void* const* d_in, const int* in_sizes, int n_in,
                              void* d_out, int out_size, void* d_ws, size_t ws_size,
                              hipStream_t stream) {
  (void)in_sizes; (void)n_in; (void)out_size; (void)ws_size;
  const float* x = (const float*)d_in[0];
  const float* wq = (const float*)d_in[1];
  const float* wk = (const float*)d_in[2];
  const float* wv = (const float*)d_in[3];
  float* out = (float*)d_out;
  char* ws = (char*)d_ws;
  const size_t S2 = 33554432;  // bytes of one fp16 split [8192][2048]
  half_t* Wth = (half_t*)ws;
  half_t* Wtl = (half_t*)(ws + 8388608);
  half_t* Qh = (half_t*)(ws + 16777216);
  half_t* Ql = (half_t*)(ws + 16777216 + S2);
  half_t* Kh = (half_t*)(ws + 16777216 + 2 * S2);
  half_t* Kl = (half_t*)(ws + 16777216 + 3 * S2);
  half_t* Vh = (half_t*)(ws + 16777216 + 4 * S2);
  half_t* Vth = (half_t*)(ws + 16777216 + 5 * S2);
  float* C2 = (float*)(ws + 16777216 + 6 * S2);
  float* Mp = C2 + 131072;       // 4 x 64 x 2048 partial maxes (2 MB)
  float* Zp = Mp + 524288;       // 4 x 64 x 2048 partial sums  (2 MB)
  half_t* Xh = (half_t*)d_out;
  half_t* Xl = (half_t*)((char*)d_out + S2);
  dim3 b(256);
  split_x<<<2048, b, 0, stream>>>(x, Xh, Xl);
  wtrans_split<<<dim3(32, 32), b, 0, stream>>>(wq, Wth, Wtl);
  proj_mfma<0><<<dim3(1024), b, 0, stream>>>(Xh, Xl, Wth, Wtl, Qh, Ql);
  wtrans_split<<<dim3(32, 32), b, 0, stream>>>(wk, Wth, Wtl);
  proj_mfma<0><<<dim3(1024), b, 0, stream>>>(Xh, Xl, Wth, Wtl, Kh, Kl);
  wtrans_split<<<dim3(32, 32), b, 0, stream>>>(wv, Wth, Wtl);
  proj_mfma<1><<<dim3(1024), b, 0, stream>>>(Xh, Xl, Wth, Wtl, Vh, nullptr);
  transpose_v<<<dim3(16, 64), b, 0, stream>>>(Vh, Vth);
  stats_mfma<<<dim3(8, 64, 4), b, 0, stream>>>(Qh, Ql, Kh, Kl, Mp, Zp);
  stats_finalize<<<dim3(512), b, 0, stream>>>(Mp, Zp, C2);
  attn_mfma<<<dim3(8, 64), dim3(512), 0, stream>>>(Qh, Ql, Kh, Kl, Vth, C2, out);
}

// Round 11
// 1100.710 us; speedup vs baseline: 1.4957x; 1.4957x over previous
//
#include <hip/hip_runtime.h>
#include <math.h>

typedef _Float16 half_t;
typedef __attribute__((ext_vector_type(8))) _Float16 f16x8;
typedef __attribute__((ext_vector_type(4))) _Float16 f16x4;
typedef __attribute__((ext_vector_type(4))) float f32x4;
typedef __attribute__((ext_vector_type(16))) float f32x16;

#define MFMA __builtin_amdgcn_mfma_f32_16x16x32_f16
#define MFMA32 __builtin_amdgcn_mfma_f32_32x32x16_f16
#define K1C (0.08838834764831845f * 1.4426950408889634f)  // SCALE * log2(e)
#define RLO (1.0f / 2048.0f)

// async global->LDS, 16B per lane (linear dest = base + lane*16)
__device__ inline void gld16(const void* g, void* l) {
  __builtin_amdgcn_global_load_lds(
      (const __attribute__((address_space(1))) uint32_t*)g,
      (__attribute__((address_space(3))) uint32_t*)l, 16, 0, 0);
}

// ---------- split fp32 -> fp16 hi + fp16 lo*2^11 ----------
__global__ __launch_bounds__(256) void split_x(const float* __restrict__ X,
                                               half_t* __restrict__ Xh,
                                               half_t* __restrict__ Xl) {
  size_t i = (size_t)blockIdx.x * 256 + threadIdx.x;
  const size_t stride = (size_t)gridDim.x * 256;
  for (size_t p = i; p < 4194304; p += stride) {
    f32x4 v = ((const f32x4*)X)[p];
    f16x4 h, l;
#pragma unroll
    for (int j = 0; j < 4; ++j) {
      half_t hh = (half_t)v[j];
      h[j] = hh;
      l[j] = (half_t)((v[j] - (float)hh) * 2048.0f);
    }
    ((f16x4*)Xh)[p] = h;
    ((f16x4*)Xl)[p] = l;
  }
}

// ---------- W[2048][2048] -> Wt[n][k] split halves ----------
__global__ __launch_bounds__(256) void wtrans_split(const float* __restrict__ W,
                                                    half_t* __restrict__ Wh,
                                                    half_t* __restrict__ Wl) {
  __shared__ float T[64][68];
  const int tid = threadIdx.x;
  const int k0 = blockIdx.x * 64, n0 = blockIdx.y * 64;
#pragma unroll
  for (int t = 0; t < 4; ++t) {
    int s = t * 256 + tid;
    int kr = s >> 4, nc = (s & 15) * 4;
    f32x4 v = *(const f32x4*)&W[(size_t)(k0 + kr) * 2048 + n0 + nc];
#pragma unroll
    for (int j = 0; j < 4; ++j) T[nc + j][kr] = v[j];
  }
  __syncthreads();
#pragma unroll
  for (int t = 0; t < 4; ++t) {
    int s = t * 256 + tid;
    int nr = s >> 4, kc = (s & 15) * 4;
    f16x4 h, l;
#pragma unroll
    for (int j = 0; j < 4; ++j) {
      float q = T[nr][kc + j];
      half_t hh = (half_t)q;
      h[j] = hh;
      l[j] = (half_t)((q - (float)hh) * 2048.0f);
    }
    *(f16x4*)&Wh[(size_t)(n0 + nr) * 2048 + k0 + kc] = h;
    *(f16x4*)&Wl[(size_t)(n0 + nr) * 2048 + k0 + kc] = l;
  }
}

// ---------- projection GEMM (32x32x16 MFMA): C = X @ Wt^T, split-fp16 ----------
#define STAGE_P(nb, kn) do {                                                  \
    _Pragma("unroll")                                                         \
    for (int t_ = 0; t_ < 2; ++t_) {                                          \
      int s_ = t_ * 256 + tid;                                                \
      int row_ = s_ >> 2;                                                     \
      int lch_ = (s_ & 3) ^ ((row_ >> 1) & 3);  /* pre-swizzled source */     \
      size_t ga_ = (size_t)(m0 + row_) * 2048 + (kn) + lch_ * 8;              \
      size_t gb_ = (size_t)(n0 + row_) * 2048 + (kn) + lch_ * 8;              \
      gld16(&Xh[ga_], &sm[nb][s_ * 8]);                                       \
      gld16(&Wh[gb_], &sm[nb][4096 + s_ * 8]);                                \
      if constexpr (MODE == 0) {                                              \
        gld16(&Xl[ga_], &sm[nb][8192 + s_ * 8]);                              \
        gld16(&Wl[gb_], &sm[nb][12288 + s_ * 8]);                             \
      }                                                                       \
    }                                                                         \
  } while (0)

template <int MODE>
__global__ __launch_bounds__(256, MODE == 0 ? 2 : 4) void proj_mfma(
    const half_t* __restrict__ Xh, const half_t* __restrict__ Xl,
    const half_t* __restrict__ Wh, const half_t* __restrict__ Wl,
    half_t* __restrict__ Ch, half_t* __restrict__ Cl) {
  __shared__ half_t sm[2][MODE == 0 ? 16384 : 8192];
  const int tid = threadIdx.x;
  const int lid = blockIdx.x;
  const int swz = (lid & 7) * 128 + (lid >> 3);  // bijective XCD swizzle (1024%8==0)
  const int m0 = (swz >> 4) << 7, n0 = (swz & 15) << 7;
  const int w = tid >> 6, lane = tid & 63, r5 = lane & 31, hi = lane >> 5;
  const int wr = w >> 1, wc = w & 1;
  const int rsw = (r5 >> 1) & 3;
  f32x16 acc0[2][2], accX[2][2];
#pragma unroll
  for (int i = 0; i < 2; ++i)
#pragma unroll
    for (int j = 0; j < 2; ++j) {
#pragma unroll
      for (int r = 0; r < 16; ++r) { acc0[i][j][r] = 0.f; accX[i][j][r] = 0.f; }
    }
  STAGE_P(0, 0);
  __syncthreads();
  for (int k0 = 0; k0 < 2048; k0 += 32) {
    const int buf = (k0 >> 5) & 1;
    if (k0 < 2016) STAGE_P(buf ^ 1, k0 + 32);
#pragma unroll
    for (int ks = 0; ks < 2; ++ks) {
      const int ch = ((ks << 1) | hi) ^ rsw;
      f16x8 a0[2], a1[2], b0[2], b1[2];
#pragma unroll
      for (int i = 0; i < 2; ++i) {
        int ar = wr * 64 + i * 32 + r5;
        int br = wc * 64 + i * 32 + r5;
        a0[i] = *(const f16x8*)&sm[buf][ar * 32 + ch * 8];
        b0[i] = *(const f16x8*)&sm[buf][4096 + br * 32 + ch * 8];
        if constexpr (MODE == 0) {
          a1[i] = *(const f16x8*)&sm[buf][8192 + ar * 32 + ch * 8];
          b1[i] = *(const f16x8*)&sm[buf][12288 + br * 32 + ch * 8];
        }
      }
#pragma unroll
      for (int i = 0; i < 2; ++i)
#pragma unroll
        for (int j = 0; j < 2; ++j) {
          acc0[i][j] = MFMA32(a0[i], b0[j], acc0[i][j], 0, 0, 0);
          if constexpr (MODE == 0) {
            accX[i][j] = MFMA32(a0[i], b1[j], accX[i][j], 0, 0, 0);
            accX[i][j] = MFMA32(a1[i], b0[j], accX[i][j], 0, 0, 0);
          }
        }
    }
    __syncthreads();
  }
#pragma unroll
  for (int i = 0; i < 2; ++i)
#pragma unroll
    for (int j = 0; j < 2; ++j) {
      int mb = m0 + wr * 64 + i * 32 + 4 * hi;
      int n = n0 + wc * 64 + j * 32 + r5;
#pragma unroll
      for (int r = 0; r < 16; ++r) {
        int mrow = mb + (r & 3) + 8 * (r >> 2);
        float q;
        if constexpr (MODE == 0) q = acc0[i][j][r] + accX[i][j][r] * RLO;
        else q = acc0[i][j][r];
        half_t hh = (half_t)q;
        size_t o = (size_t)mrow * 2048 + n;
        Ch[o] = hh;
        if constexpr (MODE == 0) Cl[o] = (half_t)((q - (float)hh) * 2048.0f);
      }
    }
}

// ---------- V[bh][k][d] -> Vt[bh][d][k] ----------
__global__ __launch_bounds__(256) void transpose_v(const half_t* __restrict__ V,
                                                   half_t* __restrict__ Vt) {
  __shared__ half_t T[128 * 128];
  const int tid = threadIdx.x;
  const int bh = blockIdx.y, k0 = blockIdx.x * 128;
  const size_t base = (size_t)bh << 18;
#pragma unroll
  for (int t = 0; t < 8; ++t) {
    int s = t * 256 + tid;
    int kr = s >> 4, ch = s & 15;
    int pc = ch ^ ((kr >> 3) & 15);
    *(f16x8*)&T[kr * 128 + pc * 8] =
        *(const f16x8*)&V[base + (size_t)(k0 + kr) * 128 + ch * 8];
  }
  __syncthreads();
#pragma unroll
  for (int t = 0; t < 8; ++t) {
    int s = t * 256 + tid;
    int d = s >> 4, kc = s & 15;
    f16x8 o;
#pragma unroll
    for (int j = 0; j < 8; ++j) {
      int kr = kc * 8 + j;
      int pc = (d >> 3) ^ (kc & 15);
      o[j] = T[kr * 128 + pc * 8 + (d & 7)];
    }
    *(f16x8*)&Vt[base + (size_t)d * 2048 + k0 + kc * 8] = o;
  }
}

// ---------- column-softmax stats, q-split x4: partial (m,z) per split ----------
#define STAGE_Q(nb, qn) do {                                                  \
    int r0_ = tid >> 4, cl0_ = tid & 15;                                      \
    size_t o0_ = base + (size_t)((qn) + r0_) * 128 + ((cl0_ ^ r0_) << 3);     \
    gld16(&Qh[o0_], &sQ0[nb][tid << 3]);                                      \
    gld16(&Ql[o0_], &sQ1[nb][tid << 3]);                                      \
    int r1_ = 16 + r0_;                                                       \
    size_t o1_ = base + (size_t)((qn) + r1_) * 128 + ((cl0_ ^ (r1_ & 15)) << 3); \
    gld16(&Qh[o1_], &sQ0[nb][(256 + tid) << 3]);                              \
    gld16(&Ql[o1_], &sQ1[nb][(256 + tid) << 3]);                              \
  } while (0)

__global__ __launch_bounds__(256, 2) void stats_mfma(
    const half_t* __restrict__ Qh, const half_t* __restrict__ Ql,
    const half_t* __restrict__ Kh, const half_t* __restrict__ Kl,
    float* __restrict__ Mp, float* __restrict__ Zp) {
  __shared__ half_t sQ0[2][4096], sQ1[2][4096];
  const int tid = threadIdx.x;
  const int w = tid >> 6, lane = tid & 63, c = lane & 15, g = lane >> 4;
  const int lid = blockIdx.y * 8 + blockIdx.x;
  const int bh = (lid & 7) * 8 + ((lid >> 3) & 7);   // XCD-swizzled
  const int xb = lid >> 6;
  const int qstart = blockIdx.z << 9;                 // 512 q per split
  const size_t base = (size_t)bh << 18;
  const int kb = xb * 256 + w * 64;
  f32x4 z4 = {0.f, 0.f, 0.f, 0.f};
  f16x8 ka0[4][4], ka1[4][4];
#pragma unroll
  for (int kt = 0; kt < 4; ++kt)
#pragma unroll
    for (int ds = 0; ds < 4; ++ds) {
      size_t a = base + (size_t)(kb + kt * 16 + c) * 128 + ds * 32 + g * 8;
      ka0[kt][ds] = *(const f16x8*)&Kh[a];
      ka1[kt][ds] = *(const f16x8*)&Kl[a];
    }
  float m[4][4], z[4][4];
#pragma unroll
  for (int kt = 0; kt < 4; ++kt)
#pragma unroll
    for (int r = 0; r < 4; ++r) { m[kt][r] = -INFINITY; z[kt][r] = 0.f; }
  STAGE_Q(0, qstart);
  __syncthreads();
  for (int t = 0; t < 16; ++t) {
    const int buf = t & 1;
    if (t < 15) STAGE_Q(buf ^ 1, qstart + ((t + 1) << 5));
#pragma unroll
    for (int qh = 0; qh < 2; ++qh) {
      f16x8 q0v[4], q1v[4];
#pragma unroll
      for (int ds = 0; ds < 4; ++ds) {
        int off = ((qh << 4) | c) * 128 + ((((ds << 2) | g) ^ c) << 3);
        q0v[ds] = *(const f16x8*)&sQ0[buf][off];
        q1v[ds] = *(const f16x8*)&sQ1[buf][off];
      }
#pragma unroll
      for (int kt = 0; kt < 4; ++kt) {
        f32x4 A0 = z4, AX = z4;
#pragma unroll
        for (int ds = 0; ds < 4; ++ds) {
          A0 = MFMA(ka0[kt][ds], q0v[ds], A0, 0, 0, 0);
          AX = MFMA(ka0[kt][ds], q1v[ds], AX, 0, 0, 0);
          AX = MFMA(ka1[kt][ds], q0v[ds], AX, 0, 0, 0);
        }
#pragma unroll
        for (int r = 0; r < 4; ++r) {
          float tt = (A0[r] + AX[r] * RLO) * K1C;
          float mo = m[kt][r];
          float mn = fmaxf(mo, tt);
          float e = __builtin_amdgcn_exp2f(fminf(mo, tt) - mn);
          z[kt][r] = (tt <= mo) ? (z[kt][r] + e) : (z[kt][r] * e + 1.0f);
          m[kt][r] = mn;
        }
      }
    }
    __syncthreads();
  }
#pragma unroll
  for (int mask = 1; mask < 16; mask <<= 1)
#pragma unroll
    for (int kt = 0; kt < 4; ++kt)
#pragma unroll
      for (int r = 0; r < 4; ++r) {
        float mo = __shfl_xor(m[kt][r], mask, 64);
        float zo = __shfl_xor(z[kt][r], mask, 64);
        float mn = fmaxf(m[kt][r], mo);
        z[kt][r] = z[kt][r] * __builtin_amdgcn_exp2f(m[kt][r] - mn) +
                   zo * __builtin_amdgcn_exp2f(mo - mn);
        m[kt][r] = mn;
      }
  if (c == 0) {
    const int pb = (blockIdx.z << 17) + (bh << 11);
#pragma unroll
    for (int kt = 0; kt < 4; ++kt)
#pragma unroll
      for (int r = 0; r < 4; ++r) {
        int idx = pb + kb + kt * 16 + (g << 2) + r;
        Mp[idx] = m[kt][r];
        Zp[idx] = z[kt][r];
      }
  }
}

// ---------- merge 4 q-split partials -> C2 = m* + log2(sum z) ----------
__global__ __launch_bounds__(256) void stats_finalize(const float* __restrict__ Mp,
                                                      const float* __restrict__ Zp,
                                                      float* __restrict__ C2) {
  int i = blockIdx.x * 256 + threadIdx.x;  // 0..131071
  float m = Mp[i], z = Zp[i];
#pragma unroll
  for (int s = 1; s < 4; ++s) {
    float ms = Mp[(s << 17) + i], zs = Zp[(s << 17) + i];
    float mn = fmaxf(m, ms);
    z = z * __builtin_amdgcn_exp2f(m - mn) + zs * __builtin_amdgcn_exp2f(ms - mn);
    m = mn;
  }
  C2[i] = m + __builtin_amdgcn_logf(z);
}

// ---------- attention: 2 q-tiles (32 q) per wave, K reads amortized over both.
// LDS 69.6KB (2 blocks/CU); launch_bounds(512,2) -> 256-VGPR budget, NO SPILL
// (round 10's (512,4) forced 64 VGPR -> scratch spill -> 2.8GB HBM fetch).
#define STAGE_ATTN(nb, ktn) do {                                              \
    int r_ = tid >> 4, chl_ = tid & 15;                                       \
    size_t ro_ = base + (size_t)((ktn) + r_) * 128 + ((chl_ ^ (r_ & 15)) << 3); \
    gld16(&Kh[ro_], &sKh[nb][tid << 3]);                                      \
    gld16(&Kl[ro_], &sKl[nb][tid << 3]);                                      \
    int d_ = tid >> 2, cvl_ = tid & 3;                                        \
    gld16(&Vt[base + (size_t)d_ * 2048 + (ktn) + ((cvl_ ^ ((d_ >> 1) & 3)) << 3)], \
          &sVs[nb][tid << 3]);                                                \
  } while (0)

__global__ __launch_bounds__(512, 2) void attn_mfma(
    const half_t* __restrict__ Qh, const half_t* __restrict__ Ql,
    const half_t* __restrict__ Kh, const half_t* __restrict__ Kl,
    const half_t* __restrict__ Vt, const float* __restrict__ C2,
    float* __restrict__ O) {
  __shared__ half_t sKh[2][4096], sKl[2][4096], sVs[2][4096];
  __shared__ half_t sP[8][2][16][40];
  const int tid = threadIdx.x;
  const int w = tid >> 6, lane = tid & 63, c = lane & 15, g = lane >> 4;
  const int lid = blockIdx.y * 8 + blockIdx.x;
  const int bh = (lid & 7) * 8 + ((lid >> 3) & 7);   // XCD-swizzled
  const int qx = lid >> 6;
  const size_t base = (size_t)bh << 18;
  const int qb = qx * 256 + w * 32;                   // 32 q per wave
  const float* c2base = C2 + ((size_t)bh << 11) + (g << 2);
  f32x4 z4 = {0.f, 0.f, 0.f, 0.f};
  f16x8 qf0[2][4], qf1[2][4];
#pragma unroll
  for (int qq = 0; qq < 2; ++qq)
#pragma unroll
    for (int ds = 0; ds < 4; ++ds) {
      size_t a = base + (size_t)(qb + qq * 16 + c) * 128 + ds * 32 + g * 8;
      qf0[qq][ds] = *(const f16x8*)&Qh[a];
      qf1[qq][ds] = *(const f16x8*)&Ql[a];
    }
  f32x4 Oacc[2][8];
#pragma unroll
  for (int qq = 0; qq < 2; ++qq)
#pragma unroll
    for (int dt = 0; dt < 8; ++dt) Oacc[qq][dt] = z4;
  STAGE_ATTN(0, 0);
  __syncthreads();
  for (int t = 0; t < 64; ++t) {
    const int buf = t & 1;
    const int kt = t << 5;
    if (t < 63) STAGE_ATTN(buf ^ 1, kt + 32);
    // hoisted C2 loads (L2-hot, independent of scores)
    f32x4 c2a = *(const f32x4*)&c2base[kt];
    f32x4 c2b = *(const f32x4*)&c2base[kt + 16];
#pragma unroll
    for (int h = 0; h < 2; ++h) {
      f32x4 A0[2] = {z4, z4}, AX[2] = {z4, z4};
#pragma unroll
      for (int ds = 0; ds < 4; ++ds) {
        int off = ((h << 4) | c) * 128 + ((((ds << 2) | g) ^ c) << 3);
        f16x8 k0v = *(const f16x8*)&sKh[buf][off];
        f16x8 k1v = *(const f16x8*)&sKl[buf][off];
#pragma unroll
        for (int qq = 0; qq < 2; ++qq) {
          A0[qq] = MFMA(k0v, qf0[qq][ds], A0[qq], 0, 0, 0);
          AX[qq] = MFMA(k0v, qf1[qq][ds], AX[qq], 0, 0, 0);
          AX[qq] = MFMA(k1v, qf0[qq][ds], AX[qq], 0, 0, 0);
        }
      }
      f32x4 c2v = h ? c2b : c2a;
#pragma unroll
      for (int qq = 0; qq < 2; ++qq) {
        f16x4 pv;
#pragma unroll
        for (int r = 0; r < 4; ++r)
          pv[r] = (half_t)__builtin_amdgcn_exp2f(
              (A0[qq][r] + AX[qq][r] * RLO) * K1C - c2v[r]);
        *(f16x4*)&sP[w][qq][c][(h << 4) + (g << 2)] = pv;
      }
    }
    f16x8 pa0 = *(const f16x8*)&sP[w][0][c][g << 3];
    f16x8 pa1 = *(const f16x8*)&sP[w][1][c][g << 3];
#pragma unroll
    for (int dt = 0; dt < 8; ++dt) {
      int dd = (dt << 4) + c;
      f16x8 vb = *(const f16x8*)&sVs[buf][dd * 32 + ((g ^ ((dd >> 1) & 3)) << 3)];
      Oacc[0][dt] = MFMA(pa0, vb, Oacc[0][dt], 0, 0, 0);
      Oacc[1][dt] = MFMA(pa1, vb, Oacc[1][dt], 0, 0, 0);
    }
    __syncthreads();
  }
#pragma unroll
  for (int qq = 0; qq < 2; ++qq)
#pragma unroll
    for (int dt = 0; dt < 8; ++dt)
#pragma unroll
      for (int r = 0; r < 4; ++r)
        O[base + (size_t)(qb + qq * 16 + (g << 2) + r) * 128 + (dt << 4) + c] =
            Oacc[qq][dt][r];
}

extern "C" void kernel_launch(void* const* d_in, const int* in_sizes, int n_in,
                              void* d_out, int out_size, void* d_ws, size_t ws_size,
                              hipStream_t stream) {
  (void)in_sizes; (void)n_in; (void)out_size; (void)ws_size;
  const float* x = (const float*)d_in[0];
  const float* wq = (const float*)d_in[1];
  const float* wk = (const float*)d_in[2];
  const float* wv = (const float*)d_in[3];
  float* out = (float*)d_out;
  char* ws = (char*)d_ws;
  const size_t S2 = 33554432;  // bytes of one fp16 split [8192][2048]
  half_t* Wth = (half_t*)ws;
  half_t* Wtl = (half_t*)(ws + 8388608);
  half_t* Qh = (half_t*)(ws + 16777216);
  half_t* Ql = (half_t*)(ws + 16777216 + S2);
  half_t* Kh = (half_t*)(ws + 16777216 + 2 * S2);
  half_t* Kl = (half_t*)(ws + 16777216 + 3 * S2);
  half_t* Vh = (half_t*)(ws + 16777216 + 4 * S2);
  half_t* Vth = (half_t*)(ws + 16777216 + 5 * S2);
  float* C2 = (float*)(ws + 16777216 + 6 * S2);
  float* Mp = C2 + 131072;       // 4 x 64 x 2048 partial maxes (2 MB)
  float* Zp = Mp + 524288;       // 4 x 64 x 2048 partial sums  (2 MB)
  half_t* Xh = (half_t*)d_out;
  half_t* Xl = (half_t*)((char*)d_out + S2);
  dim3 b(256);
  split_x<<<2048, b, 0, stream>>>(x, Xh, Xl);
  wtrans_split<<<dim3(32, 32), b, 0, stream>>>(wq, Wth, Wtl);
  proj_mfma<0><<<dim3(1024), b, 0, stream>>>(Xh, Xl, Wth, Wtl, Qh, Ql);
  wtrans_split<<<dim3(32, 32), b, 0, stream>>>(wk, Wth, Wtl);
  proj_mfma<0><<<dim3(1024), b, 0, stream>>>(Xh, Xl, Wth, Wtl, Kh, Kl);
  wtrans_split<<<dim3(32, 32), b, 0, stream>>>(wv, Wth, Wtl);
  proj_mfma<1><<<dim3(1024), b, 0, stream>>>(Xh, Xl, Wth, Wtl, Vh, nullptr);
  transpose_v<<<dim3(16, 64), b, 0, stream>>>(Vh, Vth);
  stats_mfma<<<dim3(8, 64, 4), b, 0, stream>>>(Qh, Ql, Kh, Kl, Mp, Zp);
  stats_finalize<<<dim3(512), b, 0, stream>>>(Mp, Zp, C2);
  attn_mfma<<<dim3(8, 64), dim3(512), 0, stream>>>(Qh, Ql, Kh, Kl, Vth, C2, out);
}

// Round 12
// 1098.348 us; speedup vs baseline: 1.4989x; 1.0022x over previous
//
#include <hip/hip_runtime.h>
#include <math.h>

typedef _Float16 half_t;
typedef __attribute__((ext_vector_type(8))) _Float16 f16x8;
typedef __attribute__((ext_vector_type(4))) _Float16 f16x4;
typedef __attribute__((ext_vector_type(4))) float f32x4;
typedef __attribute__((ext_vector_type(16))) float f32x16;

#define MFMA __builtin_amdgcn_mfma_f32_16x16x32_f16
#define MFMA32 __builtin_amdgcn_mfma_f32_32x32x16_f16
#define K1C (0.08838834764831845f * 1.4426950408889634f)  // SCALE * log2(e)
#define RLO (1.0f / 2048.0f)

// async global->LDS, 16B per lane (linear dest = base + lane*16)
__device__ inline void gld16(const void* g, void* l) {
  __builtin_amdgcn_global_load_lds(
      (const __attribute__((address_space(1))) uint32_t*)g,
      (__attribute__((address_space(3))) uint32_t*)l, 16, 0, 0);
}

// ---------- split fp32 -> fp16 hi + fp16 lo*2^11 ----------
__global__ __launch_bounds__(256) void split_x(const float* __restrict__ X,
                                               half_t* __restrict__ Xh,
                                               half_t* __restrict__ Xl) {
  size_t i = (size_t)blockIdx.x * 256 + threadIdx.x;
  const size_t stride = (size_t)gridDim.x * 256;
  for (size_t p = i; p < 4194304; p += stride) {
    f32x4 v = ((const f32x4*)X)[p];
    f16x4 h, l;
#pragma unroll
    for (int j = 0; j < 4; ++j) {
      half_t hh = (half_t)v[j];
      h[j] = hh;
      l[j] = (half_t)((v[j] - (float)hh) * 2048.0f);
    }
    ((f16x4*)Xh)[p] = h;
    ((f16x4*)Xl)[p] = l;
  }
}

// ---------- W[2048][2048] -> Wt[n][k] split halves ----------
__global__ __launch_bounds__(256) void wtrans_split(const float* __restrict__ W,
                                                    half_t* __restrict__ Wh,
                                                    half_t* __restrict__ Wl) {
  __shared__ float T[64][68];
  const int tid = threadIdx.x;
  const int k0 = blockIdx.x * 64, n0 = blockIdx.y * 64;
#pragma unroll
  for (int t = 0; t < 4; ++t) {
    int s = t * 256 + tid;
    int kr = s >> 4, nc = (s & 15) * 4;
    f32x4 v = *(const f32x4*)&W[(size_t)(k0 + kr) * 2048 + n0 + nc];
#pragma unroll
    for (int j = 0; j < 4; ++j) T[nc + j][kr] = v[j];
  }
  __syncthreads();
#pragma unroll
  for (int t = 0; t < 4; ++t) {
    int s = t * 256 + tid;
    int nr = s >> 4, kc = (s & 15) * 4;
    f16x4 h, l;
#pragma unroll
    for (int j = 0; j < 4; ++j) {
      float q = T[nr][kc + j];
      half_t hh = (half_t)q;
      h[j] = hh;
      l[j] = (half_t)((q - (float)hh) * 2048.0f);
    }
    *(f16x4*)&Wh[(size_t)(n0 + nr) * 2048 + k0 + kc] = h;
    *(f16x4*)&Wl[(size_t)(n0 + nr) * 2048 + k0 + kc] = l;
  }
}

// ---------- projection GEMM (32x32x16 MFMA): C = X @ Wt^T, split-fp16 ----------
#define STAGE_P(nb, kn) do {                                                  \
    _Pragma("unroll")                                                         \
    for (int t_ = 0; t_ < 2; ++t_) {                                          \
      int s_ = t_ * 256 + tid;                                                \
      int row_ = s_ >> 2;                                                     \
      int lch_ = (s_ & 3) ^ ((row_ >> 1) & 3);  /* pre-swizzled source */     \
      size_t ga_ = (size_t)(m0 + row_) * 2048 + (kn) + lch_ * 8;              \
      size_t gb_ = (size_t)(n0 + row_) * 2048 + (kn) + lch_ * 8;              \
      gld16(&Xh[ga_], &sm[nb][s_ * 8]);                                       \
      gld16(&Wh[gb_], &sm[nb][4096 + s_ * 8]);                                \
      if constexpr (MODE == 0) {                                              \
        gld16(&Xl[ga_], &sm[nb][8192 + s_ * 8]);                              \
        gld16(&Wl[gb_], &sm[nb][12288 + s_ * 8]);                             \
      }                                                                       \
    }                                                                         \
  } while (0)

template <int MODE>
__global__ __launch_bounds__(256, MODE == 0 ? 2 : 4) void proj_mfma(
    const half_t* __restrict__ Xh, const half_t* __restrict__ Xl,
    const half_t* __restrict__ Wh, const half_t* __restrict__ Wl,
    half_t* __restrict__ Ch, half_t* __restrict__ Cl) {
  __shared__ half_t sm[2][MODE == 0 ? 16384 : 8192];
  const int tid = threadIdx.x;
  const int lid = blockIdx.x;
  const int swz = (lid & 7) * 128 + (lid >> 3);  // bijective XCD swizzle (1024%8==0)
  const int m0 = (swz >> 4) << 7, n0 = (swz & 15) << 7;
  const int w = tid >> 6, lane = tid & 63, r5 = lane & 31, hi = lane >> 5;
  const int wr = w >> 1, wc = w & 1;
  const int rsw = (r5 >> 1) & 3;
  f32x16 acc0[2][2], accX[2][2];
#pragma unroll
  for (int i = 0; i < 2; ++i)
#pragma unroll
    for (int j = 0; j < 2; ++j) {
#pragma unroll
      for (int r = 0; r < 16; ++r) { acc0[i][j][r] = 0.f; accX[i][j][r] = 0.f; }
    }
  STAGE_P(0, 0);
  __syncthreads();
  for (int k0 = 0; k0 < 2048; k0 += 32) {
    const int buf = (k0 >> 5) & 1;
    if (k0 < 2016) STAGE_P(buf ^ 1, k0 + 32);
#pragma unroll
    for (int ks = 0; ks < 2; ++ks) {
      const int ch = ((ks << 1) | hi) ^ rsw;
      f16x8 a0[2], a1[2], b0[2], b1[2];
#pragma unroll
      for (int i = 0; i < 2; ++i) {
        int ar = wr * 64 + i * 32 + r5;
        int br = wc * 64 + i * 32 + r5;
        a0[i] = *(const f16x8*)&sm[buf][ar * 32 + ch * 8];
        b0[i] = *(const f16x8*)&sm[buf][4096 + br * 32 + ch * 8];
        if constexpr (MODE == 0) {
          a1[i] = *(const f16x8*)&sm[buf][8192 + ar * 32 + ch * 8];
          b1[i] = *(const f16x8*)&sm[buf][12288 + br * 32 + ch * 8];
        }
      }
#pragma unroll
      for (int i = 0; i < 2; ++i)
#pragma unroll
        for (int j = 0; j < 2; ++j) {
          acc0[i][j] = MFMA32(a0[i], b0[j], acc0[i][j], 0, 0, 0);
          if constexpr (MODE == 0) {
            accX[i][j] = MFMA32(a0[i], b1[j], accX[i][j], 0, 0, 0);
            accX[i][j] = MFMA32(a1[i], b0[j], accX[i][j], 0, 0, 0);
          }
        }
    }
    __syncthreads();
  }
#pragma unroll
  for (int i = 0; i < 2; ++i)
#pragma unroll
    for (int j = 0; j < 2; ++j) {
      int mb = m0 + wr * 64 + i * 32 + 4 * hi;
      int n = n0 + wc * 64 + j * 32 + r5;
#pragma unroll
      for (int r = 0; r < 16; ++r) {
        int mrow = mb + (r & 3) + 8 * (r >> 2);
        float q;
        if constexpr (MODE == 0) q = acc0[i][j][r] + accX[i][j][r] * RLO;
        else q = acc0[i][j][r];
        half_t hh = (half_t)q;
        size_t o = (size_t)mrow * 2048 + n;
        Ch[o] = hh;
        if constexpr (MODE == 0) Cl[o] = (half_t)((q - (float)hh) * 2048.0f);
      }
    }
}

// ---------- V[bh][k][d] -> Vt[bh][d][k] ----------
__global__ __launch_bounds__(256) void transpose_v(const half_t* __restrict__ V,
                                                   half_t* __restrict__ Vt) {
  __shared__ half_t T[128 * 128];
  const int tid = threadIdx.x;
  const int bh = blockIdx.y, k0 = blockIdx.x * 128;
  const size_t base = (size_t)bh << 18;
#pragma unroll
  for (int t = 0; t < 8; ++t) {
    int s = t * 256 + tid;
    int kr = s >> 4, ch = s & 15;
    int pc = ch ^ ((kr >> 3) & 15);
    *(f16x8*)&T[kr * 128 + pc * 8] =
        *(const f16x8*)&V[base + (size_t)(k0 + kr) * 128 + ch * 8];
  }
  __syncthreads();
#pragma unroll
  for (int t = 0; t < 8; ++t) {
    int s = t * 256 + tid;
    int d = s >> 4, kc = s & 15;
    f16x8 o;
#pragma unroll
    for (int j = 0; j < 8; ++j) {
      int kr = kc * 8 + j;
      int pc = (d >> 3) ^ (kc & 15);
      o[j] = T[kr * 128 + pc * 8 + (d & 7)];
    }
    *(f16x8*)&Vt[base + (size_t)d * 2048 + k0 + kc * 8] = o;
  }
}

// ---------- column-softmax stats, q-split x4: partial (m,z) per split ----------
#define STAGE_Q(nb, qn) do {                                                  \
    int r0_ = tid >> 4, cl0_ = tid & 15;                                      \
    size_t o0_ = base + (size_t)((qn) + r0_) * 128 + ((cl0_ ^ r0_) << 3);     \
    gld16(&Qh[o0_], &sQ0[nb][tid << 3]);                                      \
    gld16(&Ql[o0_], &sQ1[nb][tid << 3]);                                      \
    int r1_ = 16 + r0_;                                                       \
    size_t o1_ = base + (size_t)((qn) + r1_) * 128 + ((cl0_ ^ (r1_ & 15)) << 3); \
    gld16(&Qh[o1_], &sQ0[nb][(256 + tid) << 3]);                              \
    gld16(&Ql[o1_], &sQ1[nb][(256 + tid) << 3]);                              \
  } while (0)

__global__ __launch_bounds__(256, 2) void stats_mfma(
    const half_t* __restrict__ Qh, const half_t* __restrict__ Ql,
    const half_t* __restrict__ Kh, const half_t* __restrict__ Kl,
    float* __restrict__ Mp, float* __restrict__ Zp) {
  __shared__ half_t sQ0[2][4096], sQ1[2][4096];
  const int tid = threadIdx.x;
  const int w = tid >> 6, lane = tid & 63, c = lane & 15, g = lane >> 4;
  const int lid = blockIdx.y * 8 + blockIdx.x;
  const int bh = (lid & 7) * 8 + ((lid >> 3) & 7);   // XCD-swizzled
  const int xb = lid >> 6;
  const int qstart = blockIdx.z << 9;                 // 512 q per split
  const size_t base = (size_t)bh << 18;
  const int kb = xb * 256 + w * 64;
  f32x4 z4 = {0.f, 0.f, 0.f, 0.f};
  f16x8 ka0[4][4], ka1[4][4];
#pragma unroll
  for (int kt = 0; kt < 4; ++kt)
#pragma unroll
    for (int ds = 0; ds < 4; ++ds) {
      size_t a = base + (size_t)(kb + kt * 16 + c) * 128 + ds * 32 + g * 8;
      ka0[kt][ds] = *(const f16x8*)&Kh[a];
      ka1[kt][ds] = *(const f16x8*)&Kl[a];
    }
  float m[4][4], z[4][4];
#pragma unroll
  for (int kt = 0; kt < 4; ++kt)
#pragma unroll
    for (int r = 0; r < 4; ++r) { m[kt][r] = -INFINITY; z[kt][r] = 0.f; }
  STAGE_Q(0, qstart);
  __syncthreads();
  for (int t = 0; t < 16; ++t) {
    const int buf = t & 1;
    if (t < 15) STAGE_Q(buf ^ 1, qstart + ((t + 1) << 5));
#pragma unroll
    for (int qh = 0; qh < 2; ++qh) {
      f16x8 q0v[4], q1v[4];
#pragma unroll
      for (int ds = 0; ds < 4; ++ds) {
        int off = ((qh << 4) | c) * 128 + ((((ds << 2) | g) ^ c) << 3);
        q0v[ds] = *(const f16x8*)&sQ0[buf][off];
        q1v[ds] = *(const f16x8*)&sQ1[buf][off];
      }
#pragma unroll
      for (int kt = 0; kt < 4; ++kt) {
        f32x4 A0 = z4, AX = z4;
#pragma unroll
        for (int ds = 0; ds < 4; ++ds) {
          A0 = MFMA(ka0[kt][ds], q0v[ds], A0, 0, 0, 0);
          AX = MFMA(ka0[kt][ds], q1v[ds], AX, 0, 0, 0);
          AX = MFMA(ka1[kt][ds], q0v[ds], AX, 0, 0, 0);
        }
#pragma unroll
        for (int r = 0; r < 4; ++r) {
          float tt = (A0[r] + AX[r] * RLO) * K1C;
          float mo = m[kt][r];
          float mn = fmaxf(mo, tt);
          float e = __builtin_amdgcn_exp2f(fminf(mo, tt) - mn);
          z[kt][r] = (tt <= mo) ? (z[kt][r] + e) : (z[kt][r] * e + 1.0f);
          m[kt][r] = mn;
        }
      }
    }
    __syncthreads();
  }
#pragma unroll
  for (int mask = 1; mask < 16; mask <<= 1)
#pragma unroll
    for (int kt = 0; kt < 4; ++kt)
#pragma unroll
      for (int r = 0; r < 4; ++r) {
        float mo = __shfl_xor(m[kt][r], mask, 64);
        float zo = __shfl_xor(z[kt][r], mask, 64);
        float mn = fmaxf(m[kt][r], mo);
        z[kt][r] = z[kt][r] * __builtin_amdgcn_exp2f(m[kt][r] - mn) +
                   zo * __builtin_amdgcn_exp2f(mo - mn);
        m[kt][r] = mn;
      }
  if (c == 0) {
    const int pb = (blockIdx.z << 17) + (bh << 11);
#pragma unroll
    for (int kt = 0; kt < 4; ++kt)
#pragma unroll
      for (int r = 0; r < 4; ++r) {
        int idx = pb + kb + kt * 16 + (g << 2) + r;
        Mp[idx] = m[kt][r];
        Zp[idx] = z[kt][r];
      }
  }
}

// ---------- merge 4 q-split partials -> C2 = m* + log2(sum z) ----------
__global__ __launch_bounds__(256) void stats_finalize(const float* __restrict__ Mp,
                                                      const float* __restrict__ Zp,
                                                      float* __restrict__ C2) {
  int i = blockIdx.x * 256 + threadIdx.x;  // 0..131071
  float m = Mp[i], z = Zp[i];
#pragma unroll
  for (int s = 1; s < 4; ++s) {
    float ms = Mp[(s << 17) + i], zs = Zp[(s << 17) + i];
    float mn = fmaxf(m, ms);
    z = z * __builtin_amdgcn_exp2f(m - mn) + zs * __builtin_amdgcn_exp2f(ms - mn);
    m = mn;
  }
  C2[i] = m + __builtin_amdgcn_logf(z);
}

// ---------- attention: 2 q-tiles (32 q) per wave, K reads amortized over both.
// sP is a SINGLE wave-private [16][40] buffer time-shared by the two q-tiles
// (write P0 -> read pa0 -> overwrite with P1 -> read pa1; same-wave DS ops are
// FIFO and the P1 store targets the same addresses as the pa0 load -> true WAR,
// compiler cannot reorder). LDS = 59392 B -> 2 blocks/CU (threshold ~68KB).
#define STAGE_ATTN(nb, ktn) do {                                              \
    int r_ = tid >> 4, chl_ = tid & 15;                                       \
    size_t ro_ = base + (size_t)((ktn) + r_) * 128 + ((chl_ ^ (r_ & 15)) << 3); \
    gld16(&Kh[ro_], &sKh[nb][tid << 3]);                                      \
    gld16(&Kl[ro_], &sKl[nb][tid << 3]);                                      \
    int d_ = tid >> 2, cvl_ = tid & 3;                                        \
    gld16(&Vt[base + (size_t)d_ * 2048 + (ktn) + ((cvl_ ^ ((d_ >> 1) & 3)) << 3)], \
          &sVs[nb][tid << 3]);                                                \
  } while (0)

__global__ __launch_bounds__(512, 2) void attn_mfma(
    const half_t* __restrict__ Qh, const half_t* __restrict__ Ql,
    const half_t* __restrict__ Kh, const half_t* __restrict__ Kl,
    const half_t* __restrict__ Vt, const float* __restrict__ C2,
    float* __restrict__ O) {
  __shared__ half_t sKh[2][4096], sKl[2][4096], sVs[2][4096];
  __shared__ half_t sP[8][16][40];
  const int tid = threadIdx.x;
  const int w = tid >> 6, lane = tid & 63, c = lane & 15, g = lane >> 4;
  const int lid = blockIdx.y * 8 + blockIdx.x;
  const int bh = (lid & 7) * 8 + ((lid >> 3) & 7);   // XCD-swizzled
  const int qx = lid >> 6;
  const size_t base = (size_t)bh << 18;
  const int qb = qx * 256 + w * 32;                   // 32 q per wave
  const float* c2base = C2 + ((size_t)bh << 11) + (g << 2);
  f32x4 z4 = {0.f, 0.f, 0.f, 0.f};
  f16x8 qf0[2][4], qf1[2][4];
#pragma unroll
  for (int qq = 0; qq < 2; ++qq)
#pragma unroll
    for (int ds = 0; ds < 4; ++ds) {
      size_t a = base + (size_t)(qb + qq * 16 + c) * 128 + ds * 32 + g * 8;
      qf0[qq][ds] = *(const f16x8*)&Qh[a];
      qf1[qq][ds] = *(const f16x8*)&Ql[a];
    }
  f32x4 Oacc[2][8];
#pragma unroll
  for (int qq = 0; qq < 2; ++qq)
#pragma unroll
    for (int dt = 0; dt < 8; ++dt) Oacc[qq][dt] = z4;
  STAGE_ATTN(0, 0);
  __syncthreads();
  for (int t = 0; t < 64; ++t) {
    const int buf = t & 1;
    const int kt = t << 5;
    if (t < 63) STAGE_ATTN(buf ^ 1, kt + 32);
    // hoisted C2 loads (L2-hot, independent of scores)
    f32x4 c2a = *(const f32x4*)&c2base[kt];
    f32x4 c2b = *(const f32x4*)&c2base[kt + 16];
    f16x4 pv[2][2];  // [qq][h], static indexing only
#pragma unroll
    for (int h = 0; h < 2; ++h) {
      f32x4 A0[2] = {z4, z4}, AX[2] = {z4, z4};
#pragma unroll
      for (int ds = 0; ds < 4; ++ds) {
        int off = ((h << 4) | c) * 128 + ((((ds << 2) | g) ^ c) << 3);
        f16x8 k0v = *(const f16x8*)&sKh[buf][off];
        f16x8 k1v = *(const f16x8*)&sKl[buf][off];
#pragma unroll
        for (int qq = 0; qq < 2; ++qq) {
          A0[qq] = MFMA(k0v, qf0[qq][ds], A0[qq], 0, 0, 0);
          AX[qq] = MFMA(k0v, qf1[qq][ds], AX[qq], 0, 0, 0);
          AX[qq] = MFMA(k1v, qf0[qq][ds], AX[qq], 0, 0, 0);
        }
      }
      f32x4 c2v = h ? c2b : c2a;
#pragma unroll
      for (int qq = 0; qq < 2; ++qq)
#pragma unroll
        for (int r = 0; r < 4; ++r)
          pv[qq][h][r] = (half_t)__builtin_amdgcn_exp2f(
              (A0[qq][r] + AX[qq][r] * RLO) * K1C - c2v[r]);
    }
    // time-shared P buffer: qq=0 write+read, then qq=1 overwrite+read
    *(f16x4*)&sP[w][c][(g << 2)] = pv[0][0];
    *(f16x4*)&sP[w][c][16 + (g << 2)] = pv[0][1];
    f16x8 pa0 = *(const f16x8*)&sP[w][c][g << 3];
    *(f16x4*)&sP[w][c][(g << 2)] = pv[1][0];
    *(f16x4*)&sP[w][c][16 + (g << 2)] = pv[1][1];
    f16x8 pa1 = *(const f16x8*)&sP[w][c][g << 3];
#pragma unroll
    for (int dt = 0; dt < 8; ++dt) {
      int dd = (dt << 4) + c;
      f16x8 vb = *(const f16x8*)&sVs[buf][dd * 32 + ((g ^ ((dd >> 1) & 3)) << 3)];
      Oacc[0][dt] = MFMA(pa0, vb, Oacc[0][dt], 0, 0, 0);
      Oacc[1][dt] = MFMA(pa1, vb, Oacc[1][dt], 0, 0, 0);
    }
    __syncthreads();
  }
#pragma unroll
  for (int qq = 0; qq < 2; ++qq)
#pragma unroll
    for (int dt = 0; dt < 8; ++dt)
#pragma unroll
      for (int r = 0; r < 4; ++r)
        O[base + (size_t)(qb + qq * 16 + (g << 2) + r) * 128 + (dt << 4) + c] =
            Oacc[qq][dt][r];
}

extern "C" void kernel_launch(void* const* d_in, const int* in_sizes, int n_in,
                              void* d_out, int out_size, void* d_ws, size_t ws_size,
                              hipStream_t stream) {
  (void)in_sizes; (void)n_in; (void)out_size; (void)ws_size;
  const float* x = (const float*)d_in[0];
  const float* wq = (const float*)d_in[1];
  const float* wk = (const float*)d_in[2];
  const float* wv = (const float*)d_in[3];
  float* out = (float*)d_out;
  char* ws = (char*)d_ws;
  const size_t S2 = 33554432;  // bytes of one fp16 split [8192][2048]
  half_t* Wth = (half_t*)ws;
  half_t* Wtl = (half_t*)(ws + 8388608);
  half_t* Qh = (half_t*)(ws + 16777216);
  half_t* Ql = (half_t*)(ws + 16777216 + S2);
  half_t* Kh = (half_t*)(ws + 16777216 + 2 * S2);
  half_t* Kl = (half_t*)(ws + 16777216 + 3 * S2);
  half_t* Vh = (half_t*)(ws + 16777216 + 4 * S2);
  half_t* Vth = (half_t*)(ws + 16777216 + 5 * S2);
  float* C2 = (float*)(ws + 16777216 + 6 * S2);
  float* Mp = C2 + 131072;       // 4 x 64 x 2048 partial maxes (2 MB)
  float* Zp = Mp + 524288;       // 4 x 64 x 2048 partial sums  (2 MB)
  half_t* Xh = (half_t*)d_out;
  half_t* Xl = (half_t*)((char*)d_out + S2);
  dim3 b(256);
  split_x<<<2048, b, 0, stream>>>(x, Xh, Xl);
  wtrans_split<<<dim3(32, 32), b, 0, stream>>>(wq, Wth, Wtl);
  proj_mfma<0><<<dim3(1024), b, 0, stream>>>(Xh, Xl, Wth, Wtl, Qh, Ql);
  wtrans_split<<<dim3(32, 32), b, 0, stream>>>(wk, Wth, Wtl);
  proj_mfma<0><<<dim3(1024), b, 0, stream>>>(Xh, Xl, Wth, Wtl, Kh, Kl);
  wtrans_split<<<dim3(32, 32), b, 0, stream>>>(wv, Wth, Wtl);
  proj_mfma<1><<<dim3(1024), b, 0, stream>>>(Xh, Xl, Wth, Wtl, Vh, nullptr);
  transpose_v<<<dim3(16, 64), b, 0, stream>>>(Vh, Vth);
  stats_mfma<<<dim3(8, 64, 4), b, 0, stream>>>(Qh, Ql, Kh, Kl, Mp, Zp);
  stats_finalize<<<dim3(512), b, 0, stream>>>(Mp, Zp, C2);
  attn_mfma<<<dim3(8, 64), dim3(512), 0, stream>>>(Qh, Ql, Kh, Kl, Vth, C2, out);
}

// Round 13
// 1075.325 us; speedup vs baseline: 1.5310x; 1.0214x over previous
//
#include <hip/hip_runtime.h>
#include <math.h>

typedef _Float16 half_t;
typedef __attribute__((ext_vector_type(8))) _Float16 f16x8;
typedef __attribute__((ext_vector_type(4))) _Float16 f16x4;
typedef __attribute__((ext_vector_type(4))) float f32x4;
typedef __attribute__((ext_vector_type(16))) float f32x16;

#define MFMA __builtin_amdgcn_mfma_f32_16x16x32_f16
#define MFMA32 __builtin_amdgcn_mfma_f32_32x32x16_f16
#define K1C (0.08838834764831845f * 1.4426950408889634f)  // SCALE * log2(e)
#define RLO (1.0f / 2048.0f)

// async global->LDS, 16B per lane (linear dest = base + lane*16)
__device__ inline void gld16(const void* g, void* l) {
  __builtin_amdgcn_global_load_lds(
      (const __attribute__((address_space(1))) uint32_t*)g,
      (__attribute__((address_space(3))) uint32_t*)l, 16, 0, 0);
}

// ---------- split fp32 -> fp16 hi + fp16 lo*2^11 ----------
__global__ __launch_bounds__(256) void split_x(const float* __restrict__ X,
                                               half_t* __restrict__ Xh,
                                               half_t* __restrict__ Xl) {
  size_t i = (size_t)blockIdx.x * 256 + threadIdx.x;
  const size_t stride = (size_t)gridDim.x * 256;
  for (size_t p = i; p < 4194304; p += stride) {
    f32x4 v = ((const f32x4*)X)[p];
    f16x4 h, l;
#pragma unroll
    for (int j = 0; j < 4; ++j) {
      half_t hh = (half_t)v[j];
      h[j] = hh;
      l[j] = (half_t)((v[j] - (float)hh) * 2048.0f);
    }
    ((f16x4*)Xh)[p] = h;
    ((f16x4*)Xl)[p] = l;
  }
}

// ---------- W[2048][2048] -> Wt[n][k] split halves ----------
__global__ __launch_bounds__(256) void wtrans_split(const float* __restrict__ W,
                                                    half_t* __restrict__ Wh,
                                                    half_t* __restrict__ Wl) {
  __shared__ float T[64][68];
  const int tid = threadIdx.x;
  const int k0 = blockIdx.x * 64, n0 = blockIdx.y * 64;
#pragma unroll
  for (int t = 0; t < 4; ++t) {
    int s = t * 256 + tid;
    int kr = s >> 4, nc = (s & 15) * 4;
    f32x4 v = *(const f32x4*)&W[(size_t)(k0 + kr) * 2048 + n0 + nc];
#pragma unroll
    for (int j = 0; j < 4; ++j) T[nc + j][kr] = v[j];
  }
  __syncthreads();
#pragma unroll
  for (int t = 0; t < 4; ++t) {
    int s = t * 256 + tid;
    int nr = s >> 4, kc = (s & 15) * 4;
    f16x4 h, l;
#pragma unroll
    for (int j = 0; j < 4; ++j) {
      float q = T[nr][kc + j];
      half_t hh = (half_t)q;
      h[j] = hh;
      l[j] = (half_t)((q - (float)hh) * 2048.0f);
    }
    *(f16x4*)&Wh[(size_t)(n0 + nr) * 2048 + k0 + kc] = h;
    *(f16x4*)&Wl[(size_t)(n0 + nr) * 2048 + k0 + kc] = l;
  }
}

// ---------- projection GEMM (32x32x16 MFMA): C = X @ Wt^T, split-fp16 ----------
#define STAGE_P(nb, kn) do {                                                  \
    _Pragma("unroll")                                                         \
    for (int t_ = 0; t_ < 2; ++t_) {                                          \
      int s_ = t_ * 256 + tid;                                                \
      int row_ = s_ >> 2;                                                     \
      int lch_ = (s_ & 3) ^ ((row_ >> 1) & 3);  /* pre-swizzled source */     \
      size_t ga_ = (size_t)(m0 + row_) * 2048 + (kn) + lch_ * 8;              \
      size_t gb_ = (size_t)(n0 + row_) * 2048 + (kn) + lch_ * 8;              \
      gld16(&Xh[ga_], &sm[nb][s_ * 8]);                                       \
      gld16(&Wh[gb_], &sm[nb][4096 + s_ * 8]);                                \
      if constexpr (MODE == 0) {                                              \
        gld16(&Xl[ga_], &sm[nb][8192 + s_ * 8]);                              \
        gld16(&Wl[gb_], &sm[nb][12288 + s_ * 8]);                             \
      }                                                                       \
    }                                                                         \
  } while (0)

template <int MODE>
__global__ __launch_bounds__(256, MODE == 0 ? 2 : 4) void proj_mfma(
    const half_t* __restrict__ Xh, const half_t* __restrict__ Xl,
    const half_t* __restrict__ Wh, const half_t* __restrict__ Wl,
    half_t* __restrict__ Ch, half_t* __restrict__ Cl) {
  __shared__ half_t sm[2][MODE == 0 ? 16384 : 8192];
  const int tid = threadIdx.x;
  const int lid = blockIdx.x;
  const int swz = (lid & 7) * 128 + (lid >> 3);  // bijective XCD swizzle (1024%8==0)
  const int m0 = (swz >> 4) << 7, n0 = (swz & 15) << 7;
  const int w = tid >> 6, lane = tid & 63, r5 = lane & 31, hi = lane >> 5;
  const int wr = w >> 1, wc = w & 1;
  const int rsw = (r5 >> 1) & 3;
  f32x16 acc0[2][2], accX[2][2];
#pragma unroll
  for (int i = 0; i < 2; ++i)
#pragma unroll
    for (int j = 0; j < 2; ++j) {
#pragma unroll
      for (int r = 0; r < 16; ++r) { acc0[i][j][r] = 0.f; accX[i][j][r] = 0.f; }
    }
  STAGE_P(0, 0);
  __syncthreads();
  for (int k0 = 0; k0 < 2048; k0 += 32) {
    const int buf = (k0 >> 5) & 1;
    if (k0 < 2016) STAGE_P(buf ^ 1, k0 + 32);
#pragma unroll
    for (int ks = 0; ks < 2; ++ks) {
      const int ch = ((ks << 1) | hi) ^ rsw;
      f16x8 a0[2], a1[2], b0[2], b1[2];
#pragma unroll
      for (int i = 0; i < 2; ++i) {
        int ar = wr * 64 + i * 32 + r5;
        int br = wc * 64 + i * 32 + r5;
        a0[i] = *(const f16x8*)&sm[buf][ar * 32 + ch * 8];
        b0[i] = *(const f16x8*)&sm[buf][4096 + br * 32 + ch * 8];
        if constexpr (MODE == 0) {
          a1[i] = *(const f16x8*)&sm[buf][8192 + ar * 32 + ch * 8];
          b1[i] = *(const f16x8*)&sm[buf][12288 + br * 32 + ch * 8];
        }
      }
#pragma unroll
      for (int i = 0; i < 2; ++i)
#pragma unroll
        for (int j = 0; j < 2; ++j) {
          acc0[i][j] = MFMA32(a0[i], b0[j], acc0[i][j], 0, 0, 0);
          if constexpr (MODE == 0) {
            accX[i][j] = MFMA32(a0[i], b1[j], accX[i][j], 0, 0, 0);
            accX[i][j] = MFMA32(a1[i], b0[j], accX[i][j], 0, 0, 0);
          }
        }
    }
    __syncthreads();
  }
#pragma unroll
  for (int i = 0; i < 2; ++i)
#pragma unroll
    for (int j = 0; j < 2; ++j) {
      int mb = m0 + wr * 64 + i * 32 + 4 * hi;
      int n = n0 + wc * 64 + j * 32 + r5;
#pragma unroll
      for (int r = 0; r < 16; ++r) {
        int mrow = mb + (r & 3) + 8 * (r >> 2);
        float q;
        if constexpr (MODE == 0) q = acc0[i][j][r] + accX[i][j][r] * RLO;
        else q = acc0[i][j][r];
        half_t hh = (half_t)q;
        size_t o = (size_t)mrow * 2048 + n;
        Ch[o] = hh;
        if constexpr (MODE == 0) Cl[o] = (half_t)((q - (float)hh) * 2048.0f);
      }
    }
}

// ---------- V[bh][k][d] -> Vt[bh][d][k] ----------
__global__ __launch_bounds__(256) void transpose_v(const half_t* __restrict__ V,
                                                   half_t* __restrict__ Vt) {
  __shared__ half_t T[128 * 128];
  const int tid = threadIdx.x;
  const int bh = blockIdx.y, k0 = blockIdx.x * 128;
  const size_t base = (size_t)bh << 18;
#pragma unroll
  for (int t = 0; t < 8; ++t) {
    int s = t * 256 + tid;
    int kr = s >> 4, ch = s & 15;
    int pc = ch ^ ((kr >> 3) & 15);
    *(f16x8*)&T[kr * 128 + pc * 8] =
        *(const f16x8*)&V[base + (size_t)(k0 + kr) * 128 + ch * 8];
  }
  __syncthreads();
#pragma unroll
  for (int t = 0; t < 8; ++t) {
    int s = t * 256 + tid;
    int d = s >> 4, kc = s & 15;
    f16x8 o;
#pragma unroll
    for (int j = 0; j < 8; ++j) {
      int kr = kc * 8 + j;
      int pc = (d >> 3) ^ (kc & 15);
      o[j] = T[kr * 128 + pc * 8 + (d & 7)];
    }
    *(f16x8*)&Vt[base + (size_t)d * 2048 + k0 + kc * 8] = o;
  }
}

// ---------- column-softmax stats, q-split x4: partial (m,z) per split ----------
#define STAGE_Q(nb, qn) do {                                                  \
    int r0_ = tid >> 4, cl0_ = tid & 15;                                      \
    size_t o0_ = base + (size_t)((qn) + r0_) * 128 + ((cl0_ ^ r0_) << 3);     \
    gld16(&Qh[o0_], &sQ0[nb][tid << 3]);                                      \
    gld16(&Ql[o0_], &sQ1[nb][tid << 3]);                                      \
    int r1_ = 16 + r0_;                                                       \
    size_t o1_ = base + (size_t)((qn) + r1_) * 128 + ((cl0_ ^ (r1_ & 15)) << 3); \
    gld16(&Qh[o1_], &sQ0[nb][(256 + tid) << 3]);                              \
    gld16(&Ql[o1_], &sQ1[nb][(256 + tid) << 3]);                              \
  } while (0)

__global__ __launch_bounds__(256, 2) void stats_mfma(
    const half_t* __restrict__ Qh, const half_t* __restrict__ Ql,
    const half_t* __restrict__ Kh, const half_t* __restrict__ Kl,
    float* __restrict__ Mp, float* __restrict__ Zp) {
  __shared__ half_t sQ0[2][4096], sQ1[2][4096];
  const int tid = threadIdx.x;
  const int w = tid >> 6, lane = tid & 63, c = lane & 15, g = lane >> 4;
  const int lid = blockIdx.y * 8 + blockIdx.x;
  const int bh = (lid & 7) * 8 + ((lid >> 3) & 7);   // XCD-swizzled
  const int xb = lid >> 6;
  const int qstart = blockIdx.z << 9;                 // 512 q per split
  const size_t base = (size_t)bh << 18;
  const int kb = xb * 256 + w * 64;
  f32x4 z4 = {0.f, 0.f, 0.f, 0.f};
  f16x8 ka0[4][4], ka1[4][4];
#pragma unroll
  for (int kt = 0; kt < 4; ++kt)
#pragma unroll
    for (int ds = 0; ds < 4; ++ds) {
      size_t a = base + (size_t)(kb + kt * 16 + c) * 128 + ds * 32 + g * 8;
      ka0[kt][ds] = *(const f16x8*)&Kh[a];
      ka1[kt][ds] = *(const f16x8*)&Kl[a];
    }
  float m[4][4], z[4][4];
#pragma unroll
  for (int kt = 0; kt < 4; ++kt)
#pragma unroll
    for (int r = 0; r < 4; ++r) { m[kt][r] = -INFINITY; z[kt][r] = 0.f; }
  STAGE_Q(0, qstart);
  __syncthreads();
  for (int t = 0; t < 16; ++t) {
    const int buf = t & 1;
    if (t < 15) STAGE_Q(buf ^ 1, qstart + ((t + 1) << 5));
#pragma unroll
    for (int qh = 0; qh < 2; ++qh) {
      f16x8 q0v[4], q1v[4];
#pragma unroll
      for (int ds = 0; ds < 4; ++ds) {
        int off = ((qh << 4) | c) * 128 + ((((ds << 2) | g) ^ c) << 3);
        q0v[ds] = *(const f16x8*)&sQ0[buf][off];
        q1v[ds] = *(const f16x8*)&sQ1[buf][off];
      }
#pragma unroll
      for (int kt = 0; kt < 4; ++kt) {
        f32x4 A0 = z4, AX = z4;
#pragma unroll
        for (int ds = 0; ds < 4; ++ds) {
          A0 = MFMA(ka0[kt][ds], q0v[ds], A0, 0, 0, 0);
          AX = MFMA(ka0[kt][ds], q1v[ds], AX, 0, 0, 0);
          AX = MFMA(ka1[kt][ds], q0v[ds], AX, 0, 0, 0);
        }
#pragma unroll
        for (int r = 0; r < 4; ++r) {
          float tt = (A0[r] + AX[r] * RLO) * K1C;
          float mo = m[kt][r];
          float mn = fmaxf(mo, tt);
          float e = __builtin_amdgcn_exp2f(fminf(mo, tt) - mn);
          z[kt][r] = (tt <= mo) ? (z[kt][r] + e) : (z[kt][r] * e + 1.0f);
          m[kt][r] = mn;
        }
      }
    }
    __syncthreads();
  }
#pragma unroll
  for (int mask = 1; mask < 16; mask <<= 1)
#pragma unroll
    for (int kt = 0; kt < 4; ++kt)
#pragma unroll
      for (int r = 0; r < 4; ++r) {
        float mo = __shfl_xor(m[kt][r], mask, 64);
        float zo = __shfl_xor(z[kt][r], mask, 64);
        float mn = fmaxf(m[kt][r], mo);
        z[kt][r] = z[kt][r] * __builtin_amdgcn_exp2f(m[kt][r] - mn) +
                   zo * __builtin_amdgcn_exp2f(mo - mn);
        m[kt][r] = mn;
      }
  if (c == 0) {
    const int pb = (blockIdx.z << 17) + (bh << 11);
#pragma unroll
    for (int kt = 0; kt < 4; ++kt)
#pragma unroll
      for (int r = 0; r < 4; ++r) {
        int idx = pb + kb + kt * 16 + (g << 2) + r;
        Mp[idx] = m[kt][r];
        Zp[idx] = z[kt][r];
      }
  }
}

// ---------- merge 4 q-split partials -> C2 = m* + log2(sum z) ----------
__global__ __launch_bounds__(256) void stats_finalize(const float* __restrict__ Mp,
                                                      const float* __restrict__ Zp,
                                                      float* __restrict__ C2) {
  int i = blockIdx.x * 256 + threadIdx.x;  // 0..131071
  float m = Mp[i], z = Zp[i];
#pragma unroll
  for (int s = 1; s < 4; ++s) {
    float ms = Mp[(s << 17) + i], zs = Zp[(s << 17) + i];
    float mn = fmaxf(m, ms);
    z = z * __builtin_amdgcn_exp2f(m - mn) + zs * __builtin_amdgcn_exp2f(ms - mn);
    m = mn;
  }
  C2[i] = m + __builtin_amdgcn_logf(z);
}

// ---------- attention (round-7 best config): 8 waves x 16 q; dbuf K/V LDS;
// P=2^(t-C2); O=P@V. VGPR ~60 + small AGPR state -> 2 blocks/CU (41% occ).
// NOTE (r8-r12): 2-q-per-wave variants double Oacc AGPRs -> unified-regfile
// total >128/wave -> 1 block/CU -> net loss. Do not revisit without cutting
// total register state below 128.
#define STAGE_ATTN(nb, ktn) do {                                              \
    int r_ = tid >> 4, chl_ = tid & 15;                                       \
    size_t ro_ = base + (size_t)((ktn) + r_) * 128 + ((chl_ ^ (r_ & 15)) << 3); \
    gld16(&Kh[ro_], &sKh[nb][tid << 3]);                                      \
    gld16(&Kl[ro_], &sKl[nb][tid << 3]);                                      \
    int d_ = tid >> 2, cvl_ = tid & 3;                                        \
    gld16(&Vt[base + (size_t)d_ * 2048 + (ktn) + ((cvl_ ^ ((d_ >> 1) & 3)) << 3)], \
          &sVs[nb][tid << 3]);                                                \
  } while (0)

__global__ __launch_bounds__(512, 4) void attn_mfma(
    const half_t* __restrict__ Qh, const half_t* __restrict__ Ql,
    const half_t* __restrict__ Kh, const half_t* __restrict__ Kl,
    const half_t* __restrict__ Vt, const float* __restrict__ C2,
    float* __restrict__ O) {
  __shared__ half_t sKh[2][4096], sKl[2][4096], sVs[2][4096];
  __shared__ half_t sP[8][16][40];
  __shared__ float sC2[2048];
  const int tid = threadIdx.x;
  const int w = tid >> 6, lane = tid & 63, c = lane & 15, g = lane >> 4;
  const int lid = blockIdx.y * 16 + blockIdx.x;
  const int bh = (lid & 7) * 8 + ((lid >> 3) & 7);   // XCD-swizzled
  const int qx = lid >> 6;
  const size_t base = (size_t)bh << 18;
  const int qb = qx * 128 + w * 16;
  f32x4 z4 = {0.f, 0.f, 0.f, 0.f};
  f16x8 qf0[4], qf1[4];
#pragma unroll
  for (int ds = 0; ds < 4; ++ds) {
    size_t a = base + (size_t)(qb + c) * 128 + ds * 32 + g * 8;
    qf0[ds] = *(const f16x8*)&Qh[a];
    qf1[ds] = *(const f16x8*)&Ql[a];
  }
  f32x4 Oacc[8];
#pragma unroll
  for (int dt = 0; dt < 8; ++dt) Oacc[dt] = z4;
  ((f32x4*)sC2)[tid] = ((const f32x4*)(C2 + ((size_t)bh << 11)))[tid];
  STAGE_ATTN(0, 0);
  __syncthreads();
  for (int t = 0; t < 64; ++t) {
    const int buf = t & 1;
    const int kt = t << 5;
    if (t < 63) STAGE_ATTN(buf ^ 1, kt + 32);
#pragma unroll
    for (int h = 0; h < 2; ++h) {
      f32x4 A0 = z4, AX = z4;
#pragma unroll
      for (int ds = 0; ds < 4; ++ds) {
        int off = ((h << 4) | c) * 128 + ((((ds << 2) | g) ^ c) << 3);
        f16x8 k0v = *(const f16x8*)&sKh[buf][off];
        f16x8 k1v = *(const f16x8*)&sKl[buf][off];
        A0 = MFMA(k0v, qf0[ds], A0, 0, 0, 0);
        AX = MFMA(k0v, qf1[ds], AX, 0, 0, 0);
        AX = MFMA(k1v, qf0[ds], AX, 0, 0, 0);
      }
      f32x4 c2v = *(const f32x4*)&sC2[kt + (h << 4) + (g << 2)];
      f16x4 pv;
#pragma unroll
      for (int r = 0; r < 4; ++r)
        pv[r] = (half_t)__builtin_amdgcn_exp2f((A0[r] + AX[r] * RLO) * K1C - c2v[r]);
      *(f16x4*)&sP[w][c][(h << 4) + (g << 2)] = pv;
    }
    f16x8 pa = *(const f16x8*)&sP[w][c][g << 3];
#pragma unroll
    for (int dt = 0; dt < 8; ++dt) {
      int dd = (dt << 4) + c;
      f16x8 vb = *(const f16x8*)&sVs[buf][dd * 32 + ((g ^ ((dd >> 1) & 3)) << 3)];
      Oacc[dt] = MFMA(pa, vb, Oacc[dt], 0, 0, 0);
    }
    __syncthreads();
  }
#pragma unroll
  for (int dt = 0; dt < 8; ++dt)
#pragma unroll
    for (int r = 0; r < 4; ++r)
      O[base + (size_t)(qb + (g << 2) + r) * 128 + (dt << 4) + c] = Oacc[dt][r];
}

extern "C" void kernel_launch(void* const* d_in, const int* in_sizes, int n_in,
                              void* d_out, int out_size, void* d_ws, size_t ws_size,
                              hipStream_t stream) {
  (void)in_sizes; (void)n_in; (void)out_size; (void)ws_size;
  const float* x = (const float*)d_in[0];
  const float* wq = (const float*)d_in[1];
  const float* wk = (const float*)d_in[2];
  const float* wv = (const float*)d_in[3];
  float* out = (float*)d_out;
  char* ws = (char*)d_ws;
  const size_t S2 = 33554432;  // bytes of one fp16 split [8192][2048]
  half_t* Wth = (half_t*)ws;
  half_t* Wtl = (half_t*)(ws + 8388608);
  half_t* Qh = (half_t*)(ws + 16777216);
  half_t* Ql = (half_t*)(ws + 16777216 + S2);
  half_t* Kh = (half_t*)(ws + 16777216 + 2 * S2);
  half_t* Kl = (half_t*)(ws + 16777216 + 3 * S2);
  half_t* Vh = (half_t*)(ws + 16777216 + 4 * S2);
  half_t* Vth = (half_t*)(ws + 16777216 + 5 * S2);
  float* C2 = (float*)(ws + 16777216 + 6 * S2);
  float* Mp = C2 + 131072;       // 4 x 64 x 2048 partial maxes (2 MB)
  float* Zp = Mp + 524288;       // 4 x 64 x 2048 partial sums  (2 MB)
  half_t* Xh = (half_t*)d_out;
  half_t* Xl = (half_t*)((char*)d_out + S2);
  dim3 b(256);
  split_x<<<2048, b, 0, stream>>>(x, Xh, Xl);
  wtrans_split<<<dim3(32, 32), b, 0, stream>>>(wq, Wth, Wtl);
  proj_mfma<0><<<dim3(1024), b, 0, stream>>>(Xh, Xl, Wth, Wtl, Qh, Ql);
  wtrans_split<<<dim3(32, 32), b, 0, stream>>>(wk, Wth, Wtl);
  proj_mfma<0><<<dim3(1024), b, 0, stream>>>(Xh, Xl, Wth, Wtl, Kh, Kl);
  wtrans_split<<<dim3(32, 32), b, 0, stream>>>(wv, Wth, Wtl);
  proj_mfma<1><<<dim3(1024), b, 0, stream>>>(Xh, Xl, Wth, Wtl, Vh, nullptr);
  transpose_v<<<dim3(16, 64), b, 0, stream>>>(Vh, Vth);
  stats_mfma<<<dim3(8, 64, 4), b, 0, stream>>>(Qh, Ql, Kh, Kl, Mp, Zp);
  stats_finalize<<<dim3(512), b, 0, stream>>>(Mp, Zp, C2);
  attn_mfma<<<dim3(16, 64), dim3(512), 0, stream>>>(Qh, Ql, Kh, Kl, Vth, C2, out);
}

// Round 14
// 1067.749 us; speedup vs baseline: 1.5418x; 1.0071x over previous
//
#include <hip/hip_runtime.h>
#include <math.h>

typedef _Float16 half_t;
typedef __attribute__((ext_vector_type(8))) _Float16 f16x8;
typedef __attribute__((ext_vector_type(4))) _Float16 f16x4;
typedef __attribute__((ext_vector_type(4))) float f32x4;
typedef __attribute__((ext_vector_type(16))) float f32x16;

#define MFMA __builtin_amdgcn_mfma_f32_16x16x32_f16
#define MFMA32 __builtin_amdgcn_mfma_f32_32x32x16_f16
#define K1C (0.08838834764831845f * 1.4426950408889634f)  // SCALE * log2(e)
#define RLO (1.0f / 2048.0f)

// async global->LDS, 16B per lane (linear dest = base + lane*16)
__device__ inline void gld16(const void* g, void* l) {
  __builtin_amdgcn_global_load_lds(
      (const __attribute__((address_space(1))) uint32_t*)g,
      (__attribute__((address_space(3))) uint32_t*)l, 16, 0, 0);
}

// ---------- split fp32 -> fp16 hi + fp16 lo*2^11 ----------
__global__ __launch_bounds__(256) void split_x(const float* __restrict__ X,
                                               half_t* __restrict__ Xh,
                                               half_t* __restrict__ Xl) {
  size_t i = (size_t)blockIdx.x * 256 + threadIdx.x;
  const size_t stride = (size_t)gridDim.x * 256;
  for (size_t p = i; p < 4194304; p += stride) {
    f32x4 v = ((const f32x4*)X)[p];
    f16x4 h, l;
#pragma unroll
    for (int j = 0; j < 4; ++j) {
      half_t hh = (half_t)v[j];
      h[j] = hh;
      l[j] = (half_t)((v[j] - (float)hh) * 2048.0f);
    }
    ((f16x4*)Xh)[p] = h;
    ((f16x4*)Xl)[p] = l;
  }
}

// ---------- W[2048][2048] -> Wt[n][k] split halves ----------
__global__ __launch_bounds__(256) void wtrans_split(const float* __restrict__ W,
                                                    half_t* __restrict__ Wh,
                                                    half_t* __restrict__ Wl) {
  __shared__ float T[64][68];
  const int tid = threadIdx.x;
  const int k0 = blockIdx.x * 64, n0 = blockIdx.y * 64;
#pragma unroll
  for (int t = 0; t < 4; ++t) {
    int s = t * 256 + tid;
    int kr = s >> 4, nc = (s & 15) * 4;
    f32x4 v = *(const f32x4*)&W[(size_t)(k0 + kr) * 2048 + n0 + nc];
#pragma unroll
    for (int j = 0; j < 4; ++j) T[nc + j][kr] = v[j];
  }
  __syncthreads();
#pragma unroll
  for (int t = 0; t < 4; ++t) {
    int s = t * 256 + tid;
    int nr = s >> 4, kc = (s & 15) * 4;
    f16x4 h, l;
#pragma unroll
    for (int j = 0; j < 4; ++j) {
      float q = T[nr][kc + j];
      half_t hh = (half_t)q;
      h[j] = hh;
      l[j] = (half_t)((q - (float)hh) * 2048.0f);
    }
    *(f16x4*)&Wh[(size_t)(n0 + nr) * 2048 + k0 + kc] = h;
    *(f16x4*)&Wl[(size_t)(n0 + nr) * 2048 + k0 + kc] = l;
  }
}

// ---------- projection GEMM (32x32x16 MFMA): C = X @ Wt^T, split-fp16 ----------
#define STAGE_P(nb, kn) do {                                                  \
    _Pragma("unroll")                                                         \
    for (int t_ = 0; t_ < 2; ++t_) {                                          \
      int s_ = t_ * 256 + tid;                                                \
      int row_ = s_ >> 2;                                                     \
      int lch_ = (s_ & 3) ^ ((row_ >> 1) & 3);  /* pre-swizzled source */     \
      size_t ga_ = (size_t)(m0 + row_) * 2048 + (kn) + lch_ * 8;              \
      size_t gb_ = (size_t)(n0 + row_) * 2048 + (kn) + lch_ * 8;              \
      gld16(&Xh[ga_], &sm[nb][s_ * 8]);                                       \
      gld16(&Wh[gb_], &sm[nb][4096 + s_ * 8]);                                \
      if constexpr (MODE == 0) {                                              \
        gld16(&Xl[ga_], &sm[nb][8192 + s_ * 8]);                              \
        gld16(&Wl[gb_], &sm[nb][12288 + s_ * 8]);                             \
      }                                                                       \
    }                                                                         \
  } while (0)

template <int MODE>
__global__ __launch_bounds__(256, MODE == 0 ? 2 : 4) void proj_mfma(
    const half_t* __restrict__ Xh, const half_t* __restrict__ Xl,
    const half_t* __restrict__ Wh, const half_t* __restrict__ Wl,
    half_t* __restrict__ Ch, half_t* __restrict__ Cl) {
  __shared__ half_t sm[2][MODE == 0 ? 16384 : 8192];
  const int tid = threadIdx.x;
  const int lid = blockIdx.x;
  const int swz = (lid & 7) * 128 + (lid >> 3);  // bijective XCD swizzle (1024%8==0)
  const int m0 = (swz >> 4) << 7, n0 = (swz & 15) << 7;
  const int w = tid >> 6, lane = tid & 63, r5 = lane & 31, hi = lane >> 5;
  const int wr = w >> 1, wc = w & 1;
  const int rsw = (r5 >> 1) & 3;
  f32x16 acc0[2][2], accX[2][2];
#pragma unroll
  for (int i = 0; i < 2; ++i)
#pragma unroll
    for (int j = 0; j < 2; ++j) {
#pragma unroll
      for (int r = 0; r < 16; ++r) { acc0[i][j][r] = 0.f; accX[i][j][r] = 0.f; }
    }
  STAGE_P(0, 0);
  __syncthreads();
  for (int k0 = 0; k0 < 2048; k0 += 32) {
    const int buf = (k0 >> 5) & 1;
    if (k0 < 2016) STAGE_P(buf ^ 1, k0 + 32);
#pragma unroll
    for (int ks = 0; ks < 2; ++ks) {
      const int ch = ((ks << 1) | hi) ^ rsw;
      f16x8 a0[2], a1[2], b0[2], b1[2];
#pragma unroll
      for (int i = 0; i < 2; ++i) {
        int ar = wr * 64 + i * 32 + r5;
        int br = wc * 64 + i * 32 + r5;
        a0[i] = *(const f16x8*)&sm[buf][ar * 32 + ch * 8];
        b0[i] = *(const f16x8*)&sm[buf][4096 + br * 32 + ch * 8];
        if constexpr (MODE == 0) {
          a1[i] = *(const f16x8*)&sm[buf][8192 + ar * 32 + ch * 8];
          b1[i] = *(const f16x8*)&sm[buf][12288 + br * 32 + ch * 8];
        }
      }
#pragma unroll
      for (int i = 0; i < 2; ++i)
#pragma unroll
        for (int j = 0; j < 2; ++j) {
          acc0[i][j] = MFMA32(a0[i], b0[j], acc0[i][j], 0, 0, 0);
          if constexpr (MODE == 0) {
            accX[i][j] = MFMA32(a0[i], b1[j], accX[i][j], 0, 0, 0);
            accX[i][j] = MFMA32(a1[i], b0[j], accX[i][j], 0, 0, 0);
          }
        }
    }
    __syncthreads();
  }
#pragma unroll
  for (int i = 0; i < 2; ++i)
#pragma unroll
    for (int j = 0; j < 2; ++j) {
      int mb = m0 + wr * 64 + i * 32 + 4 * hi;
      int n = n0 + wc * 64 + j * 32 + r5;
#pragma unroll
      for (int r = 0; r < 16; ++r) {
        int mrow = mb + (r & 3) + 8 * (r >> 2);
        float q;
        if constexpr (MODE == 0) q = acc0[i][j][r] + accX[i][j][r] * RLO;
        else q = acc0[i][j][r];
        half_t hh = (half_t)q;
        size_t o = (size_t)mrow * 2048 + n;
        Ch[o] = hh;
        if constexpr (MODE == 0) Cl[o] = (half_t)((q - (float)hh) * 2048.0f);
      }
    }
}

// ---------- V[bh][k][d] -> Vt[bh][d][k] ----------
__global__ __launch_bounds__(256) void transpose_v(const half_t* __restrict__ V,
                                                   half_t* __restrict__ Vt) {
  __shared__ half_t T[128 * 128];
  const int tid = threadIdx.x;
  const int bh = blockIdx.y, k0 = blockIdx.x * 128;
  const size_t base = (size_t)bh << 18;
#pragma unroll
  for (int t = 0; t < 8; ++t) {
    int s = t * 256 + tid;
    int kr = s >> 4, ch = s & 15;
    int pc = ch ^ ((kr >> 3) & 15);
    *(f16x8*)&T[kr * 128 + pc * 8] =
        *(const f16x8*)&V[base + (size_t)(k0 + kr) * 128 + ch * 8];
  }
  __syncthreads();
#pragma unroll
  for (int t = 0; t < 8; ++t) {
    int s = t * 256 + tid;
    int d = s >> 4, kc = s & 15;
    f16x8 o;
#pragma unroll
    for (int j = 0; j < 8; ++j) {
      int kr = kc * 8 + j;
      int pc = (d >> 3) ^ (kc & 15);
      o[j] = T[kr * 128 + pc * 8 + (d & 7)];
    }
    *(f16x8*)&Vt[base + (size_t)d * 2048 + k0 + kc * 8] = o;
  }
}

// ---------- column-softmax stats, q-split x4: partial (m,z) per split ----------
#define STAGE_Q(nb, qn) do {                                                  \
    int r0_ = tid >> 4, cl0_ = tid & 15;                                      \
    size_t o0_ = base + (size_t)((qn) + r0_) * 128 + ((cl0_ ^ r0_) << 3);     \
    gld16(&Qh[o0_], &sQ0[nb][tid << 3]);                                      \
    gld16(&Ql[o0_], &sQ1[nb][tid << 3]);                                      \
    int r1_ = 16 + r0_;                                                       \
    size_t o1_ = base + (size_t)((qn) + r1_) * 128 + ((cl0_ ^ (r1_ & 15)) << 3); \
    gld16(&Qh[o1_], &sQ0[nb][(256 + tid) << 3]);                              \
    gld16(&Ql[o1_], &sQ1[nb][(256 + tid) << 3]);                              \
  } while (0)

__global__ __launch_bounds__(256, 2) void stats_mfma(
    const half_t* __restrict__ Qh, const half_t* __restrict__ Ql,
    const half_t* __restrict__ Kh, const half_t* __restrict__ Kl,
    float* __restrict__ Mp, float* __restrict__ Zp) {
  __shared__ half_t sQ0[2][4096], sQ1[2][4096];
  const int tid = threadIdx.x;
  const int w = tid >> 6, lane = tid & 63, c = lane & 15, g = lane >> 4;
  const int lid = blockIdx.y * 8 + blockIdx.x;
  const int bh = (lid & 7) * 8 + ((lid >> 3) & 7);   // XCD-swizzled
  const int xb = lid >> 6;
  const int qstart = blockIdx.z << 9;                 // 512 q per split
  const size_t base = (size_t)bh << 18;
  const int kb = xb * 256 + w * 64;
  f32x4 z4 = {0.f, 0.f, 0.f, 0.f};
  f16x8 ka0[4][4], ka1[4][4];
#pragma unroll
  for (int kt = 0; kt < 4; ++kt)
#pragma unroll
    for (int ds = 0; ds < 4; ++ds) {
      size_t a = base + (size_t)(kb + kt * 16 + c) * 128 + ds * 32 + g * 8;
      ka0[kt][ds] = *(const f16x8*)&Kh[a];
      ka1[kt][ds] = *(const f16x8*)&Kl[a];
    }
  float m[4][4], z[4][4];
#pragma unroll
  for (int kt = 0; kt < 4; ++kt)
#pragma unroll
    for (int r = 0; r < 4; ++r) { m[kt][r] = -INFINITY; z[kt][r] = 0.f; }
  STAGE_Q(0, qstart);
  __syncthreads();
  for (int t = 0; t < 16; ++t) {
    const int buf = t & 1;
    if (t < 15) STAGE_Q(buf ^ 1, qstart + ((t + 1) << 5));
#pragma unroll
    for (int qh = 0; qh < 2; ++qh) {
      f16x8 q0v[4], q1v[4];
#pragma unroll
      for (int ds = 0; ds < 4; ++ds) {
        int off = ((qh << 4) | c) * 128 + ((((ds << 2) | g) ^ c) << 3);
        q0v[ds] = *(const f16x8*)&sQ0[buf][off];
        q1v[ds] = *(const f16x8*)&sQ1[buf][off];
      }
#pragma unroll
      for (int kt = 0; kt < 4; ++kt) {
        f32x4 A0 = z4, AX = z4;
        __builtin_amdgcn_s_setprio(1);
#pragma unroll
        for (int ds = 0; ds < 4; ++ds) {
          A0 = MFMA(ka0[kt][ds], q0v[ds], A0, 0, 0, 0);
          AX = MFMA(ka0[kt][ds], q1v[ds], AX, 0, 0, 0);
          AX = MFMA(ka1[kt][ds], q0v[ds], AX, 0, 0, 0);
        }
        __builtin_amdgcn_s_setprio(0);
#pragma unroll
        for (int r = 0; r < 4; ++r) {
          float tt = (A0[r] + AX[r] * RLO) * K1C;
          float mo = m[kt][r];
          float mn = fmaxf(mo, tt);
          float e = __builtin_amdgcn_exp2f(fminf(mo, tt) - mn);
          z[kt][r] = (tt <= mo) ? (z[kt][r] + e) : (z[kt][r] * e + 1.0f);
          m[kt][r] = mn;
        }
      }
    }
    __syncthreads();
  }
#pragma unroll
  for (int mask = 1; mask < 16; mask <<= 1)
#pragma unroll
    for (int kt = 0; kt < 4; ++kt)
#pragma unroll
      for (int r = 0; r < 4; ++r) {
        float mo = __shfl_xor(m[kt][r], mask, 64);
        float zo = __shfl_xor(z[kt][r], mask, 64);
        float mn = fmaxf(m[kt][r], mo);
        z[kt][r] = z[kt][r] * __builtin_amdgcn_exp2f(m[kt][r] - mn) +
                   zo * __builtin_amdgcn_exp2f(mo - mn);
        m[kt][r] = mn;
      }
  if (c == 0) {
    const int pb = (blockIdx.z << 17) + (bh << 11);
#pragma unroll
    for (int kt = 0; kt < 4; ++kt)
#pragma unroll
      for (int r = 0; r < 4; ++r) {
        int idx = pb + kb + kt * 16 + (g << 2) + r;
        Mp[idx] = m[kt][r];
        Zp[idx] = z[kt][r];
      }
  }
}

// ---------- merge 4 q-split partials -> C2 = m* + log2(sum z) ----------
__global__ __launch_bounds__(256) void stats_finalize(const float* __restrict__ Mp,
                                                      const float* __restrict__ Zp,
                                                      float* __restrict__ C2) {
  int i = blockIdx.x * 256 + threadIdx.x;  // 0..131071
  float m = Mp[i], z = Zp[i];
#pragma unroll
  for (int s = 1; s < 4; ++s) {
    float ms = Mp[(s << 17) + i], zs = Zp[(s << 17) + i];
    float mn = fmaxf(m, ms);
    z = z * __builtin_amdgcn_exp2f(m - mn) + zs * __builtin_amdgcn_exp2f(ms - mn);
    m = mn;
  }
  C2[i] = m + __builtin_amdgcn_logf(z);
}

// ---------- attention (round-7 structure + T5 setprio around MFMA clusters) ----------
// NOTE (r8-r12): 2-q-per-wave variants double Oacc AGPRs -> unified-regfile
// total >128/wave -> 1 block/CU -> net loss. Do not revisit.
#define STAGE_ATTN(nb, ktn) do {                                              \
    int r_ = tid >> 4, chl_ = tid & 15;                                       \
    size_t ro_ = base + (size_t)((ktn) + r_) * 128 + ((chl_ ^ (r_ & 15)) << 3); \
    gld16(&Kh[ro_], &sKh[nb][tid << 3]);                                      \
    gld16(&Kl[ro_], &sKl[nb][tid << 3]);                                      \
    int d_ = tid >> 2, cvl_ = tid & 3;                                        \
    gld16(&Vt[base + (size_t)d_ * 2048 + (ktn) + ((cvl_ ^ ((d_ >> 1) & 3)) << 3)], \
          &sVs[nb][tid << 3]);                                                \
  } while (0)

__global__ __launch_bounds__(512, 4) void attn_mfma(
    const half_t* __restrict__ Qh, const half_t* __restrict__ Ql,
    const half_t* __restrict__ Kh, const half_t* __restrict__ Kl,
    const half_t* __restrict__ Vt, const float* __restrict__ C2,
    float* __restrict__ O) {
  __shared__ half_t sKh[2][4096], sKl[2][4096], sVs[2][4096];
  __shared__ half_t sP[8][16][40];
  __shared__ float sC2[2048];
  const int tid = threadIdx.x;
  const int w = tid >> 6, lane = tid & 63, c = lane & 15, g = lane >> 4;
  const int lid = blockIdx.y * 16 + blockIdx.x;
  const int bh = (lid & 7) * 8 + ((lid >> 3) & 7);   // XCD-swizzled
  const int qx = lid >> 6;
  const size_t base = (size_t)bh << 18;
  const int qb = qx * 128 + w * 16;
  f32x4 z4 = {0.f, 0.f, 0.f, 0.f};
  f16x8 qf0[4], qf1[4];
#pragma unroll
  for (int ds = 0; ds < 4; ++ds) {
    size_t a = base + (size_t)(qb + c) * 128 + ds * 32 + g * 8;
    qf0[ds] = *(const f16x8*)&Qh[a];
    qf1[ds] = *(const f16x8*)&Ql[a];
  }
  f32x4 Oacc[8];
#pragma unroll
  for (int dt = 0; dt < 8; ++dt) Oacc[dt] = z4;
  ((f32x4*)sC2)[tid] = ((const f32x4*)(C2 + ((size_t)bh << 11)))[tid];
  STAGE_ATTN(0, 0);
  __syncthreads();
  for (int t = 0; t < 64; ++t) {
    const int buf = t & 1;
    const int kt = t << 5;
    if (t < 63) STAGE_ATTN(buf ^ 1, kt + 32);
#pragma unroll
    for (int h = 0; h < 2; ++h) {
      f32x4 A0 = z4, AX = z4;
      __builtin_amdgcn_s_setprio(1);
#pragma unroll
      for (int ds = 0; ds < 4; ++ds) {
        int off = ((h << 4) | c) * 128 + ((((ds << 2) | g) ^ c) << 3);
        f16x8 k0v = *(const f16x8*)&sKh[buf][off];
        f16x8 k1v = *(const f16x8*)&sKl[buf][off];
        A0 = MFMA(k0v, qf0[ds], A0, 0, 0, 0);
        AX = MFMA(k0v, qf1[ds], AX, 0, 0, 0);
        AX = MFMA(k1v, qf0[ds], AX, 0, 0, 0);
      }
      __builtin_amdgcn_s_setprio(0);
      f32x4 c2v = *(const f32x4*)&sC2[kt + (h << 4) + (g << 2)];
      f16x4 pv;
#pragma unroll
      for (int r = 0; r < 4; ++r)
        pv[r] = (half_t)__builtin_amdgcn_exp2f((A0[r] + AX[r] * RLO) * K1C - c2v[r]);
      *(f16x4*)&sP[w][c][(h << 4) + (g << 2)] = pv;
    }
    f16x8 pa = *(const f16x8*)&sP[w][c][g << 3];
    __builtin_amdgcn_s_setprio(1);
#pragma unroll
    for (int dt = 0; dt < 8; ++dt) {
      int dd = (dt << 4) + c;
      f16x8 vb = *(const f16x8*)&sVs[buf][dd * 32 + ((g ^ ((dd >> 1) & 3)) << 3)];
      Oacc[dt] = MFMA(pa, vb, Oacc[dt], 0, 0, 0);
    }
    __builtin_amdgcn_s_setprio(0);
    __syncthreads();
  }
#pragma unroll
  for (int dt = 0; dt < 8; ++dt)
#pragma unroll
    for (int r = 0; r < 4; ++r)
      O[base + (size_t)(qb + (g << 2) + r) * 128 + (dt << 4) + c] = Oacc[dt][r];
}

extern "C" void kernel_launch(void* const* d_in, const int* in_sizes, int n_in,
                              void* d_out, int out_size, void* d_ws, size_t ws_size,
                              hipStream_t stream) {
  (void)in_sizes; (void)n_in; (void)out_size; (void)ws_size;
  const float* x = (const float*)d_in[0];
  const float* wq = (const float*)d_in[1];
  const float* wk = (const float*)d_in[2];
  const float* wv = (const float*)d_in[3];
  float* out = (float*)d_out;
  char* ws = (char*)d_ws;
  const size_t S2 = 33554432;  // bytes of one fp16 split [8192][2048]
  half_t* Wth = (half_t*)ws;
  half_t* Wtl = (half_t*)(ws + 8388608);
  half_t* Qh = (half_t*)(ws + 16777216);
  half_t* Ql = (half_t*)(ws + 16777216 + S2);
  half_t* Kh = (half_t*)(ws + 16777216 + 2 * S2);
  half_t* Kl = (half_t*)(ws + 16777216 + 3 * S2);
  half_t* Vh = (half_t*)(ws + 16777216 + 4 * S2);
  half_t* Vth = (half_t*)(ws + 16777216 + 5 * S2);
  float* C2 = (float*)(ws + 16777216 + 6 * S2);
  float* Mp = C2 + 131072;       // 4 x 64 x 2048 partial maxes (2 MB)
  float* Zp = Mp + 524288;       // 4 x 64 x 2048 partial sums  (2 MB)
  half_t* Xh = (half_t*)d_out;
  half_t* Xl = (half_t*)((char*)d_out + S2);
  dim3 b(256);
  split_x<<<2048, b, 0, stream>>>(x, Xh, Xl);
  wtrans_split<<<dim3(32, 32), b, 0, stream>>>(wq, Wth, Wtl);
  proj_mfma<0><<<dim3(1024), b, 0, stream>>>(Xh, Xl, Wth, Wtl, Qh, Ql);
  wtrans_split<<<dim3(32, 32), b, 0, stream>>>(wk, Wth, Wtl);
  proj_mfma<0><<<dim3(1024), b, 0, stream>>>(Xh, Xl, Wth, Wtl, Kh, Kl);
  wtrans_split<<<dim3(32, 32), b, 0, stream>>>(wv, Wth, Wtl);
  proj_mfma<1><<<dim3(1024), b, 0, stream>>>(Xh, Xl, Wth, Wtl, Vh, nullptr);
  transpose_v<<<dim3(16, 64), b, 0, stream>>>(Vh, Vth);
  stats_mfma<<<dim3(8, 64, 4), b, 0, stream>>>(Qh, Ql, Kh, Kl, Mp, Zp);
  stats_finalize<<<dim3(512), b, 0, stream>>>(Mp, Zp, C2);
  attn_mfma<<<dim3(16, 64), dim3(512), 0, stream>>>(Qh, Ql, Kh, Kl, Vth, C2, out);
}

// Round 15
// 1056.474 us; speedup vs baseline: 1.5583x; 1.0107x over previous
//
#include <hip/hip_runtime.h>
#include <math.h>

typedef _Float16 half_t;
typedef __attribute__((ext_vector_type(8))) _Float16 f16x8;
typedef __attribute__((ext_vector_type(4))) _Float16 f16x4;
typedef __attribute__((ext_vector_type(4))) float f32x4;
typedef __attribute__((ext_vector_type(16))) float f32x16;

#define MFMA __builtin_amdgcn_mfma_f32_16x16x32_f16
#define MFMA32 __builtin_amdgcn_mfma_f32_32x32x16_f16
#define K1C (0.08838834764831845f * 1.4426950408889634f)  // SCALE * log2(e)

// async global->LDS, 16B per lane (linear dest = base + lane*16)
__device__ inline void gld16(const void* g, void* l) {
  __builtin_amdgcn_global_load_lds(
      (const __attribute__((address_space(1))) uint32_t*)g,
      (__attribute__((address_space(3))) uint32_t*)l, 16, 0, 0);
}

// ---------- split fp32 -> fp16 hi + fp16 lo (UNSCALED residual; stays normal-range
// for all but |x|<~0.12 whose lost correction is negligible on 2048-length dots) ----------
__global__ __launch_bounds__(256) void split_x(const float* __restrict__ X,
                                               half_t* __restrict__ Xh,
                                               half_t* __restrict__ Xl) {
  size_t i = (size_t)blockIdx.x * 256 + threadIdx.x;
  const size_t stride = (size_t)gridDim.x * 256;
  for (size_t p = i; p < 4194304; p += stride) {
    f32x4 v = ((const f32x4*)X)[p];
    f16x4 h, l;
#pragma unroll
    for (int j = 0; j < 4; ++j) {
      half_t hh = (half_t)v[j];
      h[j] = hh;
      l[j] = (half_t)(v[j] - (float)hh);
    }
    ((f16x4*)Xh)[p] = h;
    ((f16x4*)Xl)[p] = l;
  }
}

// ---------- W[2048][2048] -> Wt[n][k] split halves (unscaled lo) ----------
__global__ __launch_bounds__(256) void wtrans_split(const float* __restrict__ W,
                                                    half_t* __restrict__ Wh,
                                                    half_t* __restrict__ Wl) {
  __shared__ float T[64][68];
  const int tid = threadIdx.x;
  const int k0 = blockIdx.x * 64, n0 = blockIdx.y * 64;
#pragma unroll
  for (int t = 0; t < 4; ++t) {
    int s = t * 256 + tid;
    int kr = s >> 4, nc = (s & 15) * 4;
    f32x4 v = *(const f32x4*)&W[(size_t)(k0 + kr) * 2048 + n0 + nc];
#pragma unroll
    for (int j = 0; j < 4; ++j) T[nc + j][kr] = v[j];
  }
  __syncthreads();
#pragma unroll
  for (int t = 0; t < 4; ++t) {
    int s = t * 256 + tid;
    int nr = s >> 4, kc = (s & 15) * 4;
    f16x4 h, l;
#pragma unroll
    for (int j = 0; j < 4; ++j) {
      float q = T[nr][kc + j];
      half_t hh = (half_t)q;
      h[j] = hh;
      l[j] = (half_t)(q - (float)hh);
    }
    *(f16x4*)&Wh[(size_t)(n0 + nr) * 2048 + k0 + kc] = h;
    *(f16x4*)&Wl[(size_t)(n0 + nr) * 2048 + k0 + kc] = l;
  }
}

// ---------- projection GEMM (32x32x16 MFMA): C = X @ Wt^T, split-fp16 ----------
// Unscaled lo -> all 3 product terms share one accumulator (halves acc regs,
// drops the RLO-combine epilogue).
#define STAGE_P(nb, kn) do {                                                  \
    _Pragma("unroll")                                                         \
    for (int t_ = 0; t_ < 2; ++t_) {                                          \
      int s_ = t_ * 256 + tid;                                                \
      int row_ = s_ >> 2;                                                     \
      int lch_ = (s_ & 3) ^ ((row_ >> 1) & 3);  /* pre-swizzled source */     \
      size_t ga_ = (size_t)(m0 + row_) * 2048 + (kn) + lch_ * 8;              \
      size_t gb_ = (size_t)(n0 + row_) * 2048 + (kn) + lch_ * 8;              \
      gld16(&Xh[ga_], &sm[nb][s_ * 8]);                                       \
      gld16(&Wh[gb_], &sm[nb][4096 + s_ * 8]);                                \
      if constexpr (MODE == 0) {                                              \
        gld16(&Xl[ga_], &sm[nb][8192 + s_ * 8]);                              \
        gld16(&Wl[gb_], &sm[nb][12288 + s_ * 8]);                             \
      }                                                                       \
    }                                                                         \
  } while (0)

template <int MODE>
__global__ __launch_bounds__(256, MODE == 0 ? 2 : 4) void proj_mfma(
    const half_t* __restrict__ Xh, const half_t* __restrict__ Xl,
    const half_t* __restrict__ Wh, const half_t* __restrict__ Wl,
    half_t* __restrict__ Ch, half_t* __restrict__ Cl) {
  __shared__ half_t sm[2][MODE == 0 ? 16384 : 8192];
  const int tid = threadIdx.x;
  const int lid = blockIdx.x;
  const int swz = (lid & 7) * 128 + (lid >> 3);  // bijective XCD swizzle (1024%8==0)
  const int m0 = (swz >> 4) << 7, n0 = (swz & 15) << 7;
  const int w = tid >> 6, lane = tid & 63, r5 = lane & 31, hi = lane >> 5;
  const int wr = w >> 1, wc = w & 1;
  const int rsw = (r5 >> 1) & 3;
  f32x16 acc[2][2];
#pragma unroll
  for (int i = 0; i < 2; ++i)
#pragma unroll
    for (int j = 0; j < 2; ++j)
#pragma unroll
      for (int r = 0; r < 16; ++r) acc[i][j][r] = 0.f;
  STAGE_P(0, 0);
  __syncthreads();
  for (int k0 = 0; k0 < 2048; k0 += 32) {
    const int buf = (k0 >> 5) & 1;
    if (k0 < 2016) STAGE_P(buf ^ 1, k0 + 32);
#pragma unroll
    for (int ks = 0; ks < 2; ++ks) {
      const int ch = ((ks << 1) | hi) ^ rsw;
      f16x8 a0[2], a1[2], b0[2], b1[2];
#pragma unroll
      for (int i = 0; i < 2; ++i) {
        int ar = wr * 64 + i * 32 + r5;
        int br = wc * 64 + i * 32 + r5;
        a0[i] = *(const f16x8*)&sm[buf][ar * 32 + ch * 8];
        b0[i] = *(const f16x8*)&sm[buf][4096 + br * 32 + ch * 8];
        if constexpr (MODE == 0) {
          a1[i] = *(const f16x8*)&sm[buf][8192 + ar * 32 + ch * 8];
          b1[i] = *(const f16x8*)&sm[buf][12288 + br * 32 + ch * 8];
        }
      }
#pragma unroll
      for (int i = 0; i < 2; ++i)
#pragma unroll
        for (int j = 0; j < 2; ++j) {
          acc[i][j] = MFMA32(a0[i], b0[j], acc[i][j], 0, 0, 0);
          if constexpr (MODE == 0) {
            acc[i][j] = MFMA32(a0[i], b1[j], acc[i][j], 0, 0, 0);
            acc[i][j] = MFMA32(a1[i], b0[j], acc[i][j], 0, 0, 0);
          }
        }
    }
    __syncthreads();
  }
#pragma unroll
  for (int i = 0; i < 2; ++i)
#pragma unroll
    for (int j = 0; j < 2; ++j) {
      int mb = m0 + wr * 64 + i * 32 + 4 * hi;
      int n = n0 + wc * 64 + j * 32 + r5;
#pragma unroll
      for (int r = 0; r < 16; ++r) {
        int mrow = mb + (r & 3) + 8 * (r >> 2);
        float q = acc[i][j][r];
        half_t hh = (half_t)q;
        size_t o = (size_t)mrow * 2048 + n;
        Ch[o] = hh;
        if constexpr (MODE == 0) Cl[o] = (half_t)(q - (float)hh);
      }
    }
}

// ---------- V[bh][k][d] -> Vt[bh][d][k] ----------
__global__ __launch_bounds__(256) void transpose_v(const half_t* __restrict__ V,
                                                   half_t* __restrict__ Vt) {
  __shared__ half_t T[128 * 128];
  const int tid = threadIdx.x;
  const int bh = blockIdx.y, k0 = blockIdx.x * 128;
  const size_t base = (size_t)bh << 18;
#pragma unroll
  for (int t = 0; t < 8; ++t) {
    int s = t * 256 + tid;
    int kr = s >> 4, ch = s & 15;
    int pc = ch ^ ((kr >> 3) & 15);
    *(f16x8*)&T[kr * 128 + pc * 8] =
        *(const f16x8*)&V[base + (size_t)(k0 + kr) * 128 + ch * 8];
  }
  __syncthreads();
#pragma unroll
  for (int t = 0; t < 8; ++t) {
    int s = t * 256 + tid;
    int d = s >> 4, kc = s & 15;
    f16x8 o;
#pragma unroll
    for (int j = 0; j < 8; ++j) {
      int kr = kc * 8 + j;
      int pc = (d >> 3) ^ (kc & 15);
      o[j] = T[kr * 128 + pc * 8 + (d & 7)];
    }
    *(f16x8*)&Vt[base + (size_t)d * 2048 + k0 + kc * 8] = o;
  }
}

// ---------- column-softmax stats, q-split x4: partial (m,z) per split ----------
#define STAGE_Q(nb, qn) do {                                                  \
    int r0_ = tid >> 4, cl0_ = tid & 15;                                      \
    size_t o0_ = base + (size_t)((qn) + r0_) * 128 + ((cl0_ ^ r0_) << 3);     \
    gld16(&Qh[o0_], &sQ0[nb][tid << 3]);                                      \
    gld16(&Ql[o0_], &sQ1[nb][tid << 3]);                                      \
    int r1_ = 16 + r0_;                                                       \
    size_t o1_ = base + (size_t)((qn) + r1_) * 128 + ((cl0_ ^ (r1_ & 15)) << 3); \
    gld16(&Qh[o1_], &sQ0[nb][(256 + tid) << 3]);                              \
    gld16(&Ql[o1_], &sQ1[nb][(256 + tid) << 3]);                              \
  } while (0)

__global__ __launch_bounds__(256, 2) void stats_mfma(
    const half_t* __restrict__ Qh, const half_t* __restrict__ Ql,
    const half_t* __restrict__ Kh, const half_t* __restrict__ Kl,
    float* __restrict__ Mp, float* __restrict__ Zp) {
  __shared__ half_t sQ0[2][4096], sQ1[2][4096];
  const int tid = threadIdx.x;
  const int w = tid >> 6, lane = tid & 63, c = lane & 15, g = lane >> 4;
  const int lid = blockIdx.y * 8 + blockIdx.x;
  const int bh = (lid & 7) * 8 + ((lid >> 3) & 7);   // XCD-swizzled
  const int xb = lid >> 6;
  const int qstart = blockIdx.z << 9;                 // 512 q per split
  const size_t base = (size_t)bh << 18;
  const int kb = xb * 256 + w * 64;
  f32x4 z4 = {0.f, 0.f, 0.f, 0.f};
  f16x8 ka0[4][4], ka1[4][4];
#pragma unroll
  for (int kt = 0; kt < 4; ++kt)
#pragma unroll
    for (int ds = 0; ds < 4; ++ds) {
      size_t a = base + (size_t)(kb + kt * 16 + c) * 128 + ds * 32 + g * 8;
      ka0[kt][ds] = *(const f16x8*)&Kh[a];
      ka1[kt][ds] = *(const f16x8*)&Kl[a];
    }
  float m[4][4], z[4][4];
#pragma unroll
  for (int kt = 0; kt < 4; ++kt)
#pragma unroll
    for (int r = 0; r < 4; ++r) { m[kt][r] = -INFINITY; z[kt][r] = 0.f; }
  STAGE_Q(0, qstart);
  __syncthreads();
  for (int t = 0; t < 16; ++t) {
    const int buf = t & 1;
    if (t < 15) STAGE_Q(buf ^ 1, qstart + ((t + 1) << 5));
#pragma unroll
    for (int qh = 0; qh < 2; ++qh) {
      f16x8 q0v[4], q1v[4];
#pragma unroll
      for (int ds = 0; ds < 4; ++ds) {
        int off = ((qh << 4) | c) * 128 + ((((ds << 2) | g) ^ c) << 3);
        q0v[ds] = *(const f16x8*)&sQ0[buf][off];
        q1v[ds] = *(const f16x8*)&sQ1[buf][off];
      }
#pragma unroll
      for (int kt = 0; kt < 4; ++kt) {
        f32x4 A = z4;
        __builtin_amdgcn_s_setprio(1);
#pragma unroll
        for (int ds = 0; ds < 4; ++ds) {
          A = MFMA(ka0[kt][ds], q0v[ds], A, 0, 0, 0);
          A = MFMA(ka0[kt][ds], q1v[ds], A, 0, 0, 0);
          A = MFMA(ka1[kt][ds], q0v[ds], A, 0, 0, 0);
        }
        __builtin_amdgcn_s_setprio(0);
#pragma unroll
        for (int r = 0; r < 4; ++r) {
          float tt = A[r] * K1C;
          float mo = m[kt][r];
          float mn = fmaxf(mo, tt);
          float e = __builtin_amdgcn_exp2f(fminf(mo, tt) - mn);
          z[kt][r] = (tt <= mo) ? (z[kt][r] + e) : (z[kt][r] * e + 1.0f);
          m[kt][r] = mn;
        }
      }
    }
    __syncthreads();
  }
#pragma unroll
  for (int mask = 1; mask < 16; mask <<= 1)
#pragma unroll
    for (int kt = 0; kt < 4; ++kt)
#pragma unroll
      for (int r = 0; r < 4; ++r) {
        float mo = __shfl_xor(m[kt][r], mask, 64);
        float zo = __shfl_xor(z[kt][r], mask, 64);
        float mn = fmaxf(m[kt][r], mo);
        z[kt][r] = z[kt][r] * __builtin_amdgcn_exp2f(m[kt][r] - mn) +
                   zo * __builtin_amdgcn_exp2f(mo - mn);
        m[kt][r] = mn;
      }
  if (c == 0) {
    const int pb = (blockIdx.z << 17) + (bh << 11);
#pragma unroll
    for (int kt = 0; kt < 4; ++kt)
#pragma unroll
      for (int r = 0; r < 4; ++r) {
        int idx = pb + kb + kt * 16 + (g << 2) + r;
        Mp[idx] = m[kt][r];
        Zp[idx] = z[kt][r];
      }
  }
}

// ---------- merge 4 q-split partials -> C2 = m* + log2(sum z) ----------
__global__ __launch_bounds__(256) void stats_finalize(const float* __restrict__ Mp,
                                                      const float* __restrict__ Zp,
                                                      float* __restrict__ C2) {
  int i = blockIdx.x * 256 + threadIdx.x;  // 0..131071
  float m = Mp[i], z = Zp[i];
#pragma unroll
  for (int s = 1; s < 4; ++s) {
    float ms = Mp[(s << 17) + i], zs = Zp[(s << 17) + i];
    float mn = fmaxf(m, ms);
    z = z * __builtin_amdgcn_exp2f(m - mn) + zs * __builtin_amdgcn_exp2f(ms - mn);
    m = mn;
  }
  C2[i] = m + __builtin_amdgcn_logf(z);
}

// ---------- attention (round-7 structure + T5 setprio; single-acc scores) ----------
// NOTE (r8-r12): 2-q-per-wave variants double Oacc AGPRs -> unified-regfile
// total >128/wave -> 1 block/CU -> net loss. Do not revisit.
#define STAGE_ATTN(nb, ktn) do {                                              \
    int r_ = tid >> 4, chl_ = tid & 15;                                       \
    size_t ro_ = base + (size_t)((ktn) + r_) * 128 + ((chl_ ^ (r_ & 15)) << 3); \
    gld16(&Kh[ro_], &sKh[nb][tid << 3]);                                      \
    gld16(&Kl[ro_], &sKl[nb][tid << 3]);                                      \
    int d_ = tid >> 2, cvl_ = tid & 3;                                        \
    gld16(&Vt[base + (size_t)d_ * 2048 + (ktn) + ((cvl_ ^ ((d_ >> 1) & 3)) << 3)], \
          &sVs[nb][tid << 3]);                                                \
  } while (0)

__global__ __launch_bounds__(512, 4) void attn_mfma(
    const half_t* __restrict__ Qh, const half_t* __restrict__ Ql,
    const half_t* __restrict__ Kh, const half_t* __restrict__ Kl,
    const half_t* __restrict__ Vt, const float* __restrict__ C2,
    float* __restrict__ O) {
  __shared__ half_t sKh[2][4096], sKl[2][4096], sVs[2][4096];
  __shared__ half_t sP[8][16][40];
  __shared__ float sC2[2048];
  const int tid = threadIdx.x;
  const int w = tid >> 6, lane = tid & 63, c = lane & 15, g = lane >> 4;
  const int lid = blockIdx.y * 16 + blockIdx.x;
  const int bh = (lid & 7) * 8 + ((lid >> 3) & 7);   // XCD-swizzled
  const int qx = lid >> 6;
  const size_t base = (size_t)bh << 18;
  const int qb = qx * 128 + w * 16;
  f32x4 z4 = {0.f, 0.f, 0.f, 0.f};
  f16x8 qf0[4], qf1[4];
#pragma unroll
  for (int ds = 0; ds < 4; ++ds) {
    size_t a = base + (size_t)(qb + c) * 128 + ds * 32 + g * 8;
    qf0[ds] = *(const f16x8*)&Qh[a];
    qf1[ds] = *(const f16x8*)&Ql[a];
  }
  f32x4 Oacc[8];
#pragma unroll
  for (int dt = 0; dt < 8; ++dt) Oacc[dt] = z4;
  ((f32x4*)sC2)[tid] = ((const f32x4*)(C2 + ((size_t)bh << 11)))[tid];
  STAGE_ATTN(0, 0);
  __syncthreads();
  for (int t = 0; t < 64; ++t) {
    const int buf = t & 1;
    const int kt = t << 5;
    if (t < 63) STAGE_ATTN(buf ^ 1, kt + 32);
#pragma unroll
    for (int h = 0; h < 2; ++h) {
      f32x4 A = z4;
      __builtin_amdgcn_s_setprio(1);
#pragma unroll
      for (int ds = 0; ds < 4; ++ds) {
        int off = ((h << 4) | c) * 128 + ((((ds << 2) | g) ^ c) << 3);
        f16x8 k0v = *(const f16x8*)&sKh[buf][off];
        f16x8 k1v = *(const f16x8*)&sKl[buf][off];
        A = MFMA(k0v, qf0[ds], A, 0, 0, 0);
        A = MFMA(k0v, qf1[ds], A, 0, 0, 0);
        A = MFMA(k1v, qf0[ds], A, 0, 0, 0);
      }
      __builtin_amdgcn_s_setprio(0);
      f32x4 c2v = *(const f32x4*)&sC2[kt + (h << 4) + (g << 2)];
      f16x4 pv;
#pragma unroll
      for (int r = 0; r < 4; ++r)
        pv[r] = (half_t)__builtin_amdgcn_exp2f(A[r] * K1C - c2v[r]);
      *(f16x4*)&sP[w][c][(h << 4) + (g << 2)] = pv;
    }
    f16x8 pa = *(const f16x8*)&sP[w][c][g << 3];
    __builtin_amdgcn_s_setprio(1);
#pragma unroll
    for (int dt = 0; dt < 8; ++dt) {
      int dd = (dt << 4) + c;
      f16x8 vb = *(const f16x8*)&sVs[buf][dd * 32 + ((g ^ ((dd >> 1) & 3)) << 3)];
      Oacc[dt] = MFMA(pa, vb, Oacc[dt], 0, 0, 0);
    }
    __builtin_amdgcn_s_setprio(0);
    __syncthreads();
  }
#pragma unroll
  for (int dt = 0; dt < 8; ++dt)
#pragma unroll
    for (int r = 0; r < 4; ++r)
      O[base + (size_t)(qb + (g << 2) + r) * 128 + (dt << 4) + c] = Oacc[dt][r];
}

extern "C" void kernel_launch(void* const* d_in, const int* in_sizes, int n_in,
                              void* d_out, int out_size, void* d_ws, size_t ws_size,
                              hipStream_t stream) {
  (void)in_sizes; (void)n_in; (void)out_size; (void)ws_size;
  const float* x = (const float*)d_in[0];
  const float* wq = (const float*)d_in[1];
  const float* wk = (const float*)d_in[2];
  const float* wv = (const float*)d_in[3];
  float* out = (float*)d_out;
  char* ws = (char*)d_ws;
  const size_t S2 = 33554432;  // bytes of one fp16 split [8192][2048]
  half_t* Wth = (half_t*)ws;
  half_t* Wtl = (half_t*)(ws + 8388608);
  half_t* Qh = (half_t*)(ws + 16777216);
  half_t* Ql = (half_t*)(ws + 16777216 + S2);
  half_t* Kh = (half_t*)(ws + 16777216 + 2 * S2);
  half_t* Kl = (half_t*)(ws + 16777216 + 3 * S2);
  half_t* Vh = (half_t*)(ws + 16777216 + 4 * S2);
  half_t* Vth = (half_t*)(ws + 16777216 + 5 * S2);
  float* C2 = (float*)(ws + 16777216 + 6 * S2);
  float* Mp = C2 + 131072;       // 4 x 64 x 2048 partial maxes (2 MB)
  float* Zp = Mp + 524288;       // 4 x 64 x 2048 partial sums  (2 MB)
  half_t* Xh = (half_t*)d_out;
  half_t* Xl = (half_t*)((char*)d_out + S2);
  dim3 b(256);
  split_x<<<2048, b, 0, stream>>>(x, Xh, Xl);
  wtrans_split<<<dim3(32, 32), b, 0, stream>>>(wq, Wth, Wtl);
  proj_mfma<0><<<dim3(1024), b, 0, stream>>>(Xh, Xl, Wth, Wtl, Qh, Ql);
  wtrans_split<<<dim3(32, 32), b, 0, stream>>>(wk, Wth, Wtl);
  proj_mfma<0><<<dim3(1024), b, 0, stream>>>(Xh, Xl, Wth, Wtl, Kh, Kl);
  wtrans_split<<<dim3(32, 32), b, 0, stream>>>(wv, Wth, Wtl);
  proj_mfma<1><<<dim3(1024), b, 0, stream>>>(Xh, Xl, Wth, Wtl, Vh, nullptr);
  transpose_v<<<dim3(16, 64), b, 0, stream>>>(Vh, Vth);
  stats_mfma<<<dim3(8, 64, 4), b, 0, stream>>>(Qh, Ql, Kh, Kl, Mp, Zp);
  stats_finalize<<<dim3(512), b, 0, stream>>>(Mp, Zp, C2);
  attn_mfma<<<dim3(16, 64), dim3(512), 0, stream>>>(Qh, Ql, Kh, Kl, Vth, C2, out);
}